// Round 8
// baseline (473.731 us; speedup 1.0000x reference)
//
#include <hip/hip_runtime.h>
#include <hip/hip_bf16.h>

#define S_LEN 2048
#define NT    32
#define DKC   64
#define NEGV  (-1e9f)
// 0.125 * log2(e): folds the 1/sqrt(64) scale and the exp->exp2 conversion
#define C_SC  0.18033688011112042f

typedef __attribute__((ext_vector_type(8))) short short8v;
typedef __attribute__((ext_vector_type(4))) float f32x4;
typedef __attribute__((ext_vector_type(2))) unsigned uint2v;

__device__ __forceinline__ short f2bf(float f){
  unsigned u = __builtin_bit_cast(unsigned, f);
  u += 0x7fffu + ((u >> 16) & 1u);          // RNE to bf16 (images)
  return (short)(u >> 16);
}

// pack two floats -> bf16 pair (round-half-up; P in [0,1], error <= 2^-9 rel)
__device__ __forceinline__ unsigned packbf(float a, float b){
  const unsigned ua = __builtin_bit_cast(unsigned, a) + 0x8000u;
  const unsigned ub = __builtin_bit_cast(unsigned, b) + 0x8000u;
  return (ua >> 16) | (ub & 0xFFFF0000u);
}

// masked value: keep f where bit j of nib is set, else +0.0f (2 VALU: sbfe + and)
__device__ __forceinline__ float mask_and(float f, unsigned nib, int j){
  const int m = __builtin_amdgcn_sbfe(nib, j, 1);      // 0 or 0xFFFFFFFF
  return __builtin_bit_cast(float, m & __builtin_bit_cast(int, f));
}

// swizzled element index for a [rows][64] bf16 tile (128B rows): XOR bits 3-5
__device__ __forceinline__ int swz(int row, int col){
  return (row * 64 + col) ^ ((row & 7) << 3);
}

// chunked XCD decode: all 32 q-tiles (or k-tiles) of a bh on XCD bh&7
__device__ __forceinline__ void xcd_decode(int p, int& bh, int& qt){
  const int xcd = p & 7;
  const int n   = p >> 3;
  bh = ((n >> 5) << 3) | xcd;
  qt = n & 31;
}

// ---------------- fallback staging (no-ws path) ----------------
__device__ __forceinline__ void stage_rows_bf16(short* dst, const float* src, int tid){
  const int r  = tid >> 2;
  const int c0 = (tid & 3) * 16;
  const float* p = src + (size_t)r * DKC + c0;
  float4 a0 = *(const float4*)(p);
  float4 a1 = *(const float4*)(p + 4);
  float4 a2 = *(const float4*)(p + 8);
  float4 a3 = *(const float4*)(p + 12);
  short8v s0, s1;
  s0[0]=f2bf(a0.x); s0[1]=f2bf(a0.y); s0[2]=f2bf(a0.z); s0[3]=f2bf(a0.w);
  s0[4]=f2bf(a1.x); s0[5]=f2bf(a1.y); s0[6]=f2bf(a1.z); s0[7]=f2bf(a1.w);
  s1[0]=f2bf(a2.x); s1[1]=f2bf(a2.y); s1[2]=f2bf(a2.z); s1[3]=f2bf(a2.w);
  s1[4]=f2bf(a3.x); s1[5]=f2bf(a3.y); s1[6]=f2bf(a3.z); s1[7]=f2bf(a3.w);
  *(short8v*)&dst[swz(r, c0)]     = s0;
  *(short8v*)&dst[swz(r, c0 + 8)] = s1;
}

__device__ __forceinline__ void stage_vT_bf16(short* dst, const float* src, int tid){
  const int k  = tid >> 4;
  const int d0 = (tid & 15) * 4;
  #pragma unroll
  for (int i = 0; i < 4; ++i){
    const int kk = k + 16 * i;
    const float4 v = *(const float4*)(src + (size_t)kk * DKC + d0);
    dst[swz(d0 + 0, kk)] = f2bf(v.x);
    dst[swz(d0 + 1, kk)] = f2bf(v.y);
    dst[swz(d0 + 2, kk)] = f2bf(v.z);
    dst[swz(d0 + 3, kk)] = f2bf(v.w);
  }
}

// ---------------- standalone maskpack (mode 1 only) ----------------
__global__ void maskpack_kernel(const int* __restrict__ mask, unsigned long long* __restrict__ bits){
  const int w    = blockIdx.x * 4 + (threadIdx.x >> 6);
  const int lane = threadIdx.x & 63;
  for (int i = 0; i < 64; ++i){
    const size_t word = (size_t)w * 64 + i;
    const int v = mask[word * 64 + lane];
    const unsigned long long b = __ballot(v != 0);
    if (lane == 0) bits[word] = b;
  }
}

// Convert one 64x64 tile: K -> bf16 swizzled [r][d], V -> transposed swizzled [d][k],
// Q -> plain row-major bf16; plus pack 32 mask words per block (8 per wave).
__global__ __launch_bounds__(256) void kvq_convert(
    const float* __restrict__ Kg, const float* __restrict__ Vg, const float* __restrict__ Qg,
    const int* __restrict__ mask, unsigned long long* __restrict__ bits,
    short* __restrict__ Kimg, short* __restrict__ Vimg, short* __restrict__ Qimg){
  __shared__ float Vf[64][65];
  const int tid  = threadIdx.x;
  const int wid  = tid >> 6;
  const int lane = tid & 63;
  int bh, t;
  xcd_decode(blockIdx.x, bh, t);
  const size_t tile = (size_t)bh * NT + t;
  const float* Kb = Kg + tile * (64 * 64);
  const float* Vb = Vg + tile * (64 * 64);
  const float* Qb = Qg + tile * (64 * 64);
  short* Ki = Kimg + tile * 4096;
  short* Vi = Vimg + tile * 4096;
  short* Qi = Qimg + tile * 4096;

  // mask packing: wave gw handles words gw*8 .. gw*8+7
  {
    const int gw = blockIdx.x * 4 + wid;
    #pragma unroll
    for (int i = 0; i < 8; ++i){
      const size_t word = (size_t)gw * 8 + i;
      const int v = mask[word * 64 + lane];
      const unsigned long long b = __ballot(v != 0);
      if (lane == 0) bits[word] = b;
    }
  }

  // K (swizzled) + Q (plain): direct row conversion
  {
    const int r = tid >> 2, c0 = (tid & 3) * 16;
    const float* p = Kb + (size_t)r * 64 + c0;
    float4 a0 = *(const float4*)(p);
    float4 a1 = *(const float4*)(p + 4);
    float4 a2 = *(const float4*)(p + 8);
    float4 a3 = *(const float4*)(p + 12);
    short8v s0, s1;
    s0[0]=f2bf(a0.x); s0[1]=f2bf(a0.y); s0[2]=f2bf(a0.z); s0[3]=f2bf(a0.w);
    s0[4]=f2bf(a1.x); s0[5]=f2bf(a1.y); s0[6]=f2bf(a1.z); s0[7]=f2bf(a1.w);
    s1[0]=f2bf(a2.x); s1[1]=f2bf(a2.y); s1[2]=f2bf(a2.z); s1[3]=f2bf(a2.w);
    s1[4]=f2bf(a3.x); s1[5]=f2bf(a3.y); s1[6]=f2bf(a3.z); s1[7]=f2bf(a3.w);
    *(short8v*)&Ki[swz(r, c0)]     = s0;
    *(short8v*)&Ki[swz(r, c0 + 8)] = s1;

    const float* q = Qb + (size_t)r * 64 + c0;
    float4 b0 = *(const float4*)(q);
    float4 b1 = *(const float4*)(q + 4);
    float4 b2 = *(const float4*)(q + 8);
    float4 b3 = *(const float4*)(q + 12);
    short8v t0, t1;
    t0[0]=f2bf(b0.x); t0[1]=f2bf(b0.y); t0[2]=f2bf(b0.z); t0[3]=f2bf(b0.w);
    t0[4]=f2bf(b1.x); t0[5]=f2bf(b1.y); t0[6]=f2bf(b1.z); t0[7]=f2bf(b1.w);
    t1[0]=f2bf(b2.x); t1[1]=f2bf(b2.y); t1[2]=f2bf(b2.z); t1[3]=f2bf(b2.w);
    t1[4]=f2bf(b3.x); t1[5]=f2bf(b3.y); t1[6]=f2bf(b3.z); t1[7]=f2bf(b3.w);
    *(short8v*)&Qi[r * 64 + c0]     = t0;
    *(short8v*)&Qi[r * 64 + c0 + 8] = t1;
  }
  // V: LDS transpose
  {
    const int k = tid >> 2, c0 = (tid & 3) * 16;
    const float* p = Vb + (size_t)k * 64 + c0;
    float4 a0 = *(const float4*)(p);
    float4 a1 = *(const float4*)(p + 4);
    float4 a2 = *(const float4*)(p + 8);
    float4 a3 = *(const float4*)(p + 12);
    Vf[k][c0+0]=a0.x; Vf[k][c0+1]=a0.y; Vf[k][c0+2]=a0.z; Vf[k][c0+3]=a0.w;
    Vf[k][c0+4]=a1.x; Vf[k][c0+5]=a1.y; Vf[k][c0+6]=a1.z; Vf[k][c0+7]=a1.w;
    Vf[k][c0+8]=a2.x; Vf[k][c0+9]=a2.y; Vf[k][c0+10]=a2.z; Vf[k][c0+11]=a2.w;
    Vf[k][c0+12]=a3.x; Vf[k][c0+13]=a3.y; Vf[k][c0+14]=a3.z; Vf[k][c0+15]=a3.w;
  }
  __syncthreads();
  {
    const int d = tid >> 2, k0 = (tid & 3) * 16;
    short8v s0, s1;
    #pragma unroll
    for (int i = 0; i < 8; ++i) s0[i] = f2bf(Vf[k0 + i][d]);
    #pragma unroll
    for (int i = 0; i < 8; ++i) s1[i] = f2bf(Vf[k0 + 8 + i][d]);
    *(short8v*)&Vi[swz(d, k0)]     = s0;
    *(short8v*)&Vi[swz(d, k0 + 8)] = s1;
  }
}

// ---------------- PASS 1: denominators (log2 of row sums) ----------------
__global__ __launch_bounds__(256) void pass_sum(
    const short* __restrict__ Qimg, const unsigned long long* __restrict__ bitsg,
    const short* __restrict__ Kimg, float* __restrict__ lnl)
{
  const int tid  = threadIdx.x;
  const int wid  = tid >> 6;
  const int lane = tid & 63;
  const int lh   = lane >> 4;
  const int ll   = lane & 15;

  int bh, qt;
  xcd_decode(blockIdx.x, bh, qt);
  const int qrow = qt * 64 + wid * 16 + ll;

  const short* Qib = Qimg + (size_t)bh * S_LEN * 64;
  const short* Kib = Kimg + (size_t)bh * NT * 4096;
  const unsigned long long* wbp = bitsg + (size_t)qrow * NT;

  short8v qf[2];
  qf[0] = *(const short8v*)(Qib + (size_t)qrow * 64 + lh * 8);
  qf[1] = *(const short8v*)(Qib + (size_t)qrow * 64 + 32 + lh * 8);

  float s4[4] = {0.f, 0.f, 0.f, 0.f};      // 4 independent accumulation chains
  unsigned long long wb = wbp[0];
  #pragma unroll 2
  for (int t = 0; t < NT; ++t){
    const short* Kt_ = Kib + (size_t)t * 4096;
    const unsigned long long wb_next = (t + 1 < NT) ? wbp[t + 1] : 0;
    short8v kf[8];
    #pragma unroll
    for (int kt = 0; kt < 4; ++kt){
      kf[kt*2+0] = *(const short8v*)(Kt_ + swz(kt * 16 + ll, lh * 8));
      kf[kt*2+1] = *(const short8v*)(Kt_ + swz(kt * 16 + ll, 32 + lh * 8));
    }
    #pragma unroll
    for (int kt = 0; kt < 4; ++kt){
      f32x4 a = (f32x4){0.f, 0.f, 0.f, 0.f};
      a = __builtin_amdgcn_mfma_f32_16x16x32_bf16(kf[kt*2+0], qf[0], a, 0, 0, 0);
      a = __builtin_amdgcn_mfma_f32_16x16x32_bf16(kf[kt*2+1], qf[1], a, 0, 0, 0);
      const unsigned nib = (unsigned)(wb >> (kt * 16 + lh * 4));
      #pragma unroll
      for (int j = 0; j < 4; ++j)
        s4[j] += mask_and(exp2f(a[j] * C_SC), nib, j);
    }
    wb = wb_next;
  }
  float sum = (s4[0] + s4[1]) + (s4[2] + s4[3]);
  sum += __shfl_xor(sum, 16, 64);
  sum += __shfl_xor(sum, 32, 64);
  if (lh == 0) lnl[bh * S_LEN + qrow] = __log2f(sum);
}

// ---------------- PASS 2: probs + O = P.V (half-wise, VALU-lean) ----------------
__global__ __launch_bounds__(256) void pass_out(
    const short* __restrict__ Qimg, const unsigned long long* __restrict__ bitsg,
    const short* __restrict__ Kimg, const short* __restrict__ Vimg,
    const float* __restrict__ lnl, float* __restrict__ outg, float* __restrict__ probsg)
{
  __shared__ __align__(16) short Pl[4096];   // 2KB per wave, wave-private

  const int tid  = threadIdx.x;
  const int wid  = tid >> 6;
  const int lane = tid & 63;
  const int lh   = lane >> 4;
  const int ll   = lane & 15;

  int bh, qt;
  xcd_decode(blockIdx.x, bh, qt);
  const int qrow = qt * 64 + wid * 16 + ll;

  const short* Qib = Qimg + (size_t)bh * S_LEN * 64;
  const short* Kib = Kimg + (size_t)bh * NT * 4096;
  const short* Vib = Vimg + (size_t)bh * NT * 4096;
  float* outb = outg + (size_t)bh * S_LEN * DKC;
  const unsigned long long* wbp = bitsg + (size_t)qrow * NT;
  float* prow = probsg + (size_t)bh * S_LEN * S_LEN + (size_t)qrow * S_LEN + lh * 4;

  short8v qf[2];
  qf[0] = *(const short8v*)(Qib + (size_t)qrow * 64 + lh * 8);
  qf[1] = *(const short8v*)(Qib + (size_t)qrow * 64 + 32 + lh * 8);
  const float rlog = lnl[bh * S_LEN + qrow];

  f32x4 o[4];
  #pragma unroll
  for (int dt = 0; dt < 4; ++dt) o[dt] = (f32x4){0.f, 0.f, 0.f, 0.f};

  short* Plw = &Pl[wid * 1024];

  for (int t = 0; t < NT; ++t){
    const unsigned long long wb = wbp[t];
    const short* Kt_ = Kib + (size_t)t * 4096;
    const short* Vt_ = Vib + (size_t)t * 4096;

    #pragma unroll
    for (int h = 0; h < 2; ++h){           // 32-k half: krows h*32 .. h*32+31
      short8v kf[4], vf[4];
      #pragma unroll
      for (int q = 0; q < 2; ++q){
        const int kt = h * 2 + q;
        kf[q*2+0] = *(const short8v*)(Kt_ + swz(kt * 16 + ll, lh * 8));
        kf[q*2+1] = *(const short8v*)(Kt_ + swz(kt * 16 + ll, 32 + lh * 8));
      }
      #pragma unroll
      for (int dt = 0; dt < 4; ++dt)
        vf[dt] = *(const short8v*)(Vt_ + swz(dt * 16 + ll, h * 32 + lh * 8));

      f32x4 acc[2];
      #pragma unroll
      for (int q = 0; q < 2; ++q){
        f32x4 a = (f32x4){0.f, 0.f, 0.f, 0.f};
        a = __builtin_amdgcn_mfma_f32_16x16x32_bf16(kf[q*2+0], qf[0], a, 0, 0, 0);
        a = __builtin_amdgcn_mfma_f32_16x16x32_bf16(kf[q*2+1], qf[1], a, 0, 0, 0);
        acc[q] = a;
      }

      #pragma unroll
      for (int q = 0; q < 2; ++q){
        const int kt = h * 2 + q;
        const unsigned nib = (unsigned)(wb >> (kt * 16 + lh * 4));
        float p[4];
        #pragma unroll
        for (int j = 0; j < 4; ++j)
          p[j] = mask_and(exp2f(fmaf(acc[q][j], C_SC, -rlog)), nib, j);
        f32x4 pv; pv[0]=p[0]; pv[1]=p[1]; pv[2]=p[2]; pv[3]=p[3];
        __builtin_nontemporal_store(pv, (f32x4*)&prow[t * 64 + kt * 16]);
        uint2v pk; pk[0] = packbf(p[0], p[1]); pk[1] = packbf(p[2], p[3]);
        *(uint2v*)&Plw[swz(ll, kt * 16 + lh * 4)] = pk;
      }

      const short8v pf = *(const short8v*)&Plw[swz(ll, h * 32 + lh * 8)];
      #pragma unroll
      for (int dt = 0; dt < 4; ++dt)
        o[dt] = __builtin_amdgcn_mfma_f32_16x16x32_bf16(pf, vf[dt], o[dt], 0, 0, 0);
    }
  }

  #pragma unroll
  for (int dt = 0; dt < 4; ++dt)
    #pragma unroll
    for (int j = 0; j < 4; ++j)
      __builtin_nontemporal_store(o[dt][j], &outb[(size_t)(qt * 64 + wid * 16 + lh * 4 + j) * DKC + dt * 16 + ll]);
}

// ---------------- fallback: monolithic two-pass with LDS staging ----------------
template<int BITS>
__global__ __launch_bounds__(256) void attn_fb(
    const float* __restrict__ Qg, const float* __restrict__ Kg, const float* __restrict__ Vg,
    const int* __restrict__ maskg, const unsigned long long* __restrict__ bitsg,
    float* __restrict__ outg, float* __restrict__ probsg)
{
  __shared__ __align__(16) short Kl[4096];
  __shared__ __align__(16) short Vt[4096];
  __shared__ __align__(16) short Pl[4096];

  const int tid  = threadIdx.x;
  const int wid  = tid >> 6;
  const int lane = tid & 63;
  const int lh   = lane >> 4;
  const int ll   = lane & 15;

  const int qt    = blockIdx.x & 31;
  const int bh    = blockIdx.x >> 5;
  const int qbase = qt * 64;
  const int qrow  = qbase + wid * 16 + ll;

  const float* Qb = Qg + (size_t)bh * S_LEN * DKC;
  const float* Kb = Kg + (size_t)bh * S_LEN * DKC;
  const float* Vb = Vg + (size_t)bh * S_LEN * DKC;
  float* outb   = outg   + (size_t)bh * S_LEN * DKC;
  float* probsb = probsg + (size_t)bh * S_LEN * S_LEN;

  short8v qf[2];
  #pragma unroll
  for (int h = 0; h < 2; ++h){
    const float4 a = *(const float4*)(Qb + (size_t)qrow * DKC + h * 32 + lh * 8);
    const float4 b = *(const float4*)(Qb + (size_t)qrow * DKC + h * 32 + lh * 8 + 4);
    short8v t;
    t[0]=f2bf(a.x); t[1]=f2bf(a.y); t[2]=f2bf(a.z); t[3]=f2bf(a.w);
    t[4]=f2bf(b.x); t[5]=f2bf(b.y); t[6]=f2bf(b.z); t[7]=f2bf(b.w);
    qf[h] = t;
  }

  float sum = 0.f;
  for (int t = 0; t < NT; ++t){
    __syncthreads();
    stage_rows_bf16(Kl, Kb + (size_t)t * 64 * DKC, tid);
    __syncthreads();
    unsigned long long wb = 0;
    if constexpr (BITS) wb = bitsg[(size_t)qrow * NT + t];
    #pragma unroll
    for (int kt = 0; kt < 4; ++kt){
      const short8v kf0 = *(const short8v*)&Kl[swz(kt * 16 + ll, lh * 8)];
      const short8v kf1 = *(const short8v*)&Kl[swz(kt * 16 + ll, 32 + lh * 8)];
      f32x4 a = (f32x4){0.f, 0.f, 0.f, 0.f};
      a = __builtin_amdgcn_mfma_f32_16x16x32_bf16(kf0, qf[0], a, 0, 0, 0);
      a = __builtin_amdgcn_mfma_f32_16x16x32_bf16(kf1, qf[1], a, 0, 0, 0);
      #pragma unroll
      for (int j = 0; j < 4; ++j){
        const int bi = kt * 16 + lh * 4 + j;
        int keep;
        if constexpr (BITS) keep = (int)((wb >> bi) & 1ull);
        else                keep = maskg[(size_t)qrow * S_LEN + t * 64 + bi] != 0;
        sum += exp2f(keep ? a[j] * C_SC : NEGV);
      }
    }
  }
  sum += __shfl_xor(sum, 16, 64);
  sum += __shfl_xor(sum, 32, 64);
  const float rlog = __log2f(sum);

  f32x4 o[4];
  #pragma unroll
  for (int dt = 0; dt < 4; ++dt) o[dt] = (f32x4){0.f, 0.f, 0.f, 0.f};

  for (int t = 0; t < NT; ++t){
    __syncthreads();
    stage_rows_bf16(Kl, Kb + (size_t)t * 64 * DKC, tid);
    stage_vT_bf16 (Vt, Vb + (size_t)t * 64 * DKC, tid);
    __syncthreads();
    f32x4 acc[4];
    #pragma unroll
    for (int kt = 0; kt < 4; ++kt){
      const short8v kf0 = *(const short8v*)&Kl[swz(kt * 16 + ll, lh * 8)];
      const short8v kf1 = *(const short8v*)&Kl[swz(kt * 16 + ll, 32 + lh * 8)];
      f32x4 a = (f32x4){0.f, 0.f, 0.f, 0.f};
      a = __builtin_amdgcn_mfma_f32_16x16x32_bf16(kf0, qf[0], a, 0, 0, 0);
      a = __builtin_amdgcn_mfma_f32_16x16x32_bf16(kf1, qf[1], a, 0, 0, 0);
      acc[kt] = a;
    }
    unsigned long long wb = 0;
    if constexpr (BITS) wb = bitsg[(size_t)qrow * NT + t];
    #pragma unroll
    for (int kt = 0; kt < 4; ++kt){
      float p[4];
      #pragma unroll
      for (int j = 0; j < 4; ++j){
        const int bi = kt * 16 + lh * 4 + j;
        int keep;
        if constexpr (BITS) keep = (int)((wb >> bi) & 1ull);
        else                keep = maskg[(size_t)qrow * S_LEN + t * 64 + bi] != 0;
        p[j] = exp2f(keep ? fmaf(acc[kt][j], C_SC, -rlog) : NEGV);
      }
      f32x4 pv; pv[0]=p[0]; pv[1]=p[1]; pv[2]=p[2]; pv[3]=p[3];
      __builtin_nontemporal_store(pv, (f32x4*)&probsb[(size_t)qrow * S_LEN + t * 64 + kt * 16 + lh * 4]);
      short4 ps; ps.x=f2bf(p[0]); ps.y=f2bf(p[1]); ps.z=f2bf(p[2]); ps.w=f2bf(p[3]);
      *(short4*)&Pl[wid * 1024 + swz(ll, kt * 16 + lh * 4)] = ps;
    }
    asm volatile("s_waitcnt lgkmcnt(0)" ::: "memory");
    __builtin_amdgcn_sched_barrier(0);
    #pragma unroll
    for (int k32 = 0; k32 < 2; ++k32){
      const short8v pf = *(const short8v*)&Pl[wid * 1024 + swz(ll, k32 * 32 + lh * 8)];
      #pragma unroll
      for (int dt = 0; dt < 4; ++dt){
        const short8v vf = *(const short8v*)&Vt[swz(dt * 16 + ll, k32 * 32 + lh * 8)];
        o[dt] = __builtin_amdgcn_mfma_f32_16x16x32_bf16(pf, vf, o[dt], 0, 0, 0);
      }
    }
  }

  #pragma unroll
  for (int dt = 0; dt < 4; ++dt)
    #pragma unroll
    for (int j = 0; j < 4; ++j)
      __builtin_nontemporal_store(o[dt][j], &outb[(size_t)(qbase + wid * 16 + lh * 4 + j) * DKC + dt * 16 + ll]);
}

extern "C" void kernel_launch(void* const* d_in, const int* in_sizes, int n_in,
                              void* d_out, int out_size, void* d_ws, size_t ws_size,
                              hipStream_t stream) {
  const float* Q    = (const float*)d_in[0];
  const float* K    = (const float*)d_in[1];
  const float* V    = (const float*)d_in[2];
  const int*   mask = (const int*)d_in[3];

  float* out   = (float*)d_out;
  float* probs = out + (size_t)4 * 16 * 2048 * 64;

  const size_t bitsB = (size_t)S_LEN * S_LEN / 8;          // 512 KiB
  const size_t imgB  = (size_t)64 * NT * 4096 * 2;         // 16 MiB each
  const size_t lnlB  = (size_t)64 * S_LEN * 4;             // 512 KiB
  unsigned long long* bits = (unsigned long long*)d_ws;
  short* Kimg = (short*)((char*)d_ws + bitsB);
  short* Vimg = (short*)((char*)d_ws + bitsB + imgB);
  short* Qimg = (short*)((char*)d_ws + bitsB + 2 * imgB);
  float* lnl  = (float*)((char*)d_ws + bitsB + 3 * imgB);

  int mode;
  if      (ws_size >= bitsB + 3 * imgB + lnlB) mode = 2;
  else if (ws_size >= bitsB)                   mode = 1;
  else                                         mode = 0;

  if (mode == 2){
    kvq_convert<<<64 * NT, 256, 0, stream>>>(K, V, Q, mask, bits, Kimg, Vimg, Qimg);
    pass_sum<<<64 * 32, 256, 0, stream>>>(Qimg, bits, Kimg, lnl);
    pass_out<<<64 * 32, 256, 0, stream>>>(Qimg, bits, Kimg, Vimg, lnl, out, probs);
  } else if (mode == 1){
    maskpack_kernel<<<256, 256, 0, stream>>>(mask, bits);
    attn_fb<1><<<64 * 32, 256, 0, stream>>>(Q, K, V, mask, bits, out, probs);
  } else {
    attn_fb<0><<<64 * 32, 256, 0, stream>>>(Q, K, V, mask, bits, out, probs);
  }
}

// Round 9
// 414.137 us; speedup vs baseline: 1.1439x; 1.1439x over previous
//
#include <hip/hip_runtime.h>
#include <hip/hip_bf16.h>

#define S_LEN 2048
#define NT    32
#define DKC   64
#define NEGV  (-1e9f)
// 0.125 * log2(e): folds the 1/sqrt(64) scale and the exp->exp2 conversion
#define C_SC  0.18033688011112042f

typedef __attribute__((ext_vector_type(8))) short short8v;
typedef __attribute__((ext_vector_type(4))) float f32x4;
typedef __attribute__((ext_vector_type(2))) unsigned uint2v;

__device__ __forceinline__ short f2bf(float f){
  unsigned u = __builtin_bit_cast(unsigned, f);
  u += 0x7fffu + ((u >> 16) & 1u);          // RNE to bf16 (images)
  return (short)(u >> 16);
}

// pack two floats -> bf16 pair (round-half-up; P in [0,1], error <= 2^-9 rel)
__device__ __forceinline__ unsigned packbf(float a, float b){
  const unsigned ua = __builtin_bit_cast(unsigned, a) + 0x8000u;
  const unsigned ub = __builtin_bit_cast(unsigned, b) + 0x8000u;
  return (ua >> 16) | (ub & 0xFFFF0000u);
}

// masked value: keep f where bit j of nib is set, else +0.0f (2 VALU: sbfe + and)
__device__ __forceinline__ float mask_and(float f, unsigned nib, int j){
  const int m = __builtin_amdgcn_sbfe(nib, j, 1);      // 0 or 0xFFFFFFFF
  return __builtin_bit_cast(float, m & __builtin_bit_cast(int, f));
}

// swizzled element index for a [rows][64] bf16 tile (128B rows): XOR bits 3-5
__device__ __forceinline__ int swz(int row, int col){
  return (row * 64 + col) ^ ((row & 7) << 3);
}

// chunked XCD decode: all 32 q-tiles (or k-tiles) of a bh on XCD bh&7
__device__ __forceinline__ void xcd_decode(int p, int& bh, int& qt){
  const int xcd = p & 7;
  const int n   = p >> 3;
  bh = ((n >> 5) << 3) | xcd;
  qt = n & 31;
}

// ---------------- fallback staging (no-ws path) ----------------
__device__ __forceinline__ void stage_rows_bf16(short* dst, const float* src, int tid){
  const int r  = tid >> 2;
  const int c0 = (tid & 3) * 16;
  const float* p = src + (size_t)r * DKC + c0;
  float4 a0 = *(const float4*)(p);
  float4 a1 = *(const float4*)(p + 4);
  float4 a2 = *(const float4*)(p + 8);
  float4 a3 = *(const float4*)(p + 12);
  short8v s0, s1;
  s0[0]=f2bf(a0.x); s0[1]=f2bf(a0.y); s0[2]=f2bf(a0.z); s0[3]=f2bf(a0.w);
  s0[4]=f2bf(a1.x); s0[5]=f2bf(a1.y); s0[6]=f2bf(a1.z); s0[7]=f2bf(a1.w);
  s1[0]=f2bf(a2.x); s1[1]=f2bf(a2.y); s1[2]=f2bf(a2.z); s1[3]=f2bf(a2.w);
  s1[4]=f2bf(a3.x); s1[5]=f2bf(a3.y); s1[6]=f2bf(a3.z); s1[7]=f2bf(a3.w);
  *(short8v*)&dst[swz(r, c0)]     = s0;
  *(short8v*)&dst[swz(r, c0 + 8)] = s1;
}

__device__ __forceinline__ void stage_vT_bf16(short* dst, const float* src, int tid){
  const int k  = tid >> 4;
  const int d0 = (tid & 15) * 4;
  #pragma unroll
  for (int i = 0; i < 4; ++i){
    const int kk = k + 16 * i;
    const float4 v = *(const float4*)(src + (size_t)kk * DKC + d0);
    dst[swz(d0 + 0, kk)] = f2bf(v.x);
    dst[swz(d0 + 1, kk)] = f2bf(v.y);
    dst[swz(d0 + 2, kk)] = f2bf(v.z);
    dst[swz(d0 + 3, kk)] = f2bf(v.w);
  }
}

// ---------------- standalone maskpack (mode 1 only) ----------------
__global__ void maskpack_kernel(const int* __restrict__ mask, unsigned long long* __restrict__ bits){
  const int w    = blockIdx.x * 4 + (threadIdx.x >> 6);
  const int lane = threadIdx.x & 63;
  for (int i = 0; i < 64; ++i){
    const size_t word = (size_t)w * 64 + i;
    const int v = mask[word * 64 + lane];
    const unsigned long long b = __ballot(v != 0);
    if (lane == 0) bits[word] = b;
  }
}

// Convert one 64x64 tile: K -> bf16 swizzled [r][d], V -> transposed swizzled [d][k],
// Q -> plain row-major bf16; plus pack 32 mask words per block (8 per wave).
__global__ __launch_bounds__(256) void kvq_convert(
    const float* __restrict__ Kg, const float* __restrict__ Vg, const float* __restrict__ Qg,
    const int* __restrict__ mask, unsigned long long* __restrict__ bits,
    short* __restrict__ Kimg, short* __restrict__ Vimg, short* __restrict__ Qimg){
  __shared__ float Vf[64][65];
  const int tid  = threadIdx.x;
  const int wid  = tid >> 6;
  const int lane = tid & 63;
  int bh, t;
  xcd_decode(blockIdx.x, bh, t);
  const size_t tile = (size_t)bh * NT + t;
  const float* Kb = Kg + tile * (64 * 64);
  const float* Vb = Vg + tile * (64 * 64);
  const float* Qb = Qg + tile * (64 * 64);
  short* Ki = Kimg + tile * 4096;
  short* Vi = Vimg + tile * 4096;
  short* Qi = Qimg + tile * 4096;

  // mask packing: wave gw handles words gw*8 .. gw*8+7
  {
    const int gw = blockIdx.x * 4 + wid;
    #pragma unroll
    for (int i = 0; i < 8; ++i){
      const size_t word = (size_t)gw * 8 + i;
      const int v = mask[word * 64 + lane];
      const unsigned long long b = __ballot(v != 0);
      if (lane == 0) bits[word] = b;
    }
  }

  // K (swizzled) + Q (plain): direct row conversion
  {
    const int r = tid >> 2, c0 = (tid & 3) * 16;
    const float* p = Kb + (size_t)r * 64 + c0;
    float4 a0 = *(const float4*)(p);
    float4 a1 = *(const float4*)(p + 4);
    float4 a2 = *(const float4*)(p + 8);
    float4 a3 = *(const float4*)(p + 12);
    short8v s0, s1;
    s0[0]=f2bf(a0.x); s0[1]=f2bf(a0.y); s0[2]=f2bf(a0.z); s0[3]=f2bf(a0.w);
    s0[4]=f2bf(a1.x); s0[5]=f2bf(a1.y); s0[6]=f2bf(a1.z); s0[7]=f2bf(a1.w);
    s1[0]=f2bf(a2.x); s1[1]=f2bf(a2.y); s1[2]=f2bf(a2.z); s1[3]=f2bf(a2.w);
    s1[4]=f2bf(a3.x); s1[5]=f2bf(a3.y); s1[6]=f2bf(a3.z); s1[7]=f2bf(a3.w);
    *(short8v*)&Ki[swz(r, c0)]     = s0;
    *(short8v*)&Ki[swz(r, c0 + 8)] = s1;

    const float* q = Qb + (size_t)r * 64 + c0;
    float4 b0 = *(const float4*)(q);
    float4 b1 = *(const float4*)(q + 4);
    float4 b2 = *(const float4*)(q + 8);
    float4 b3 = *(const float4*)(q + 12);
    short8v t0, t1;
    t0[0]=f2bf(b0.x); t0[1]=f2bf(b0.y); t0[2]=f2bf(b0.z); t0[3]=f2bf(b0.w);
    t0[4]=f2bf(b1.x); t0[5]=f2bf(b1.y); t0[6]=f2bf(b1.z); t0[7]=f2bf(b1.w);
    t1[0]=f2bf(b2.x); t1[1]=f2bf(b2.y); t1[2]=f2bf(b2.z); t1[3]=f2bf(b2.w);
    t1[4]=f2bf(b3.x); t1[5]=f2bf(b3.y); t1[6]=f2bf(b3.z); t1[7]=f2bf(b3.w);
    *(short8v*)&Qi[r * 64 + c0]     = t0;
    *(short8v*)&Qi[r * 64 + c0 + 8] = t1;
  }
  // V: LDS transpose
  {
    const int k = tid >> 2, c0 = (tid & 3) * 16;
    const float* p = Vb + (size_t)k * 64 + c0;
    float4 a0 = *(const float4*)(p);
    float4 a1 = *(const float4*)(p + 4);
    float4 a2 = *(const float4*)(p + 8);
    float4 a3 = *(const float4*)(p + 12);
    Vf[k][c0+0]=a0.x; Vf[k][c0+1]=a0.y; Vf[k][c0+2]=a0.z; Vf[k][c0+3]=a0.w;
    Vf[k][c0+4]=a1.x; Vf[k][c0+5]=a1.y; Vf[k][c0+6]=a1.z; Vf[k][c0+7]=a1.w;
    Vf[k][c0+8]=a2.x; Vf[k][c0+9]=a2.y; Vf[k][c0+10]=a2.z; Vf[k][c0+11]=a2.w;
    Vf[k][c0+12]=a3.x; Vf[k][c0+13]=a3.y; Vf[k][c0+14]=a3.z; Vf[k][c0+15]=a3.w;
  }
  __syncthreads();
  {
    const int d = tid >> 2, k0 = (tid & 3) * 16;
    short8v s0, s1;
    #pragma unroll
    for (int i = 0; i < 8; ++i) s0[i] = f2bf(Vf[k0 + i][d]);
    #pragma unroll
    for (int i = 0; i < 8; ++i) s1[i] = f2bf(Vf[k0 + 8 + i][d]);
    *(short8v*)&Vi[swz(d, k0)]     = s0;
    *(short8v*)&Vi[swz(d, k0 + 8)] = s1;
  }
}

// ---------------- PASS 1: denominators (log2 of row sums) ----------------
__global__ __launch_bounds__(256) void pass_sum(
    const short* __restrict__ Qimg, const unsigned long long* __restrict__ bitsg,
    const short* __restrict__ Kimg, float* __restrict__ lnl)
{
  const int tid  = threadIdx.x;
  const int wid  = tid >> 6;
  const int lane = tid & 63;
  const int lh   = lane >> 4;
  const int ll   = lane & 15;

  int bh, qt;
  xcd_decode(blockIdx.x, bh, qt);
  const int qrow = qt * 64 + wid * 16 + ll;

  const short* Qib = Qimg + (size_t)bh * S_LEN * 64;
  const short* Kib = Kimg + (size_t)bh * NT * 4096;
  const unsigned long long* wbp = bitsg + (size_t)qrow * NT;

  short8v qf[2];
  qf[0] = *(const short8v*)(Qib + (size_t)qrow * 64 + lh * 8);
  qf[1] = *(const short8v*)(Qib + (size_t)qrow * 64 + 32 + lh * 8);

  float s4[4] = {0.f, 0.f, 0.f, 0.f};      // 4 independent accumulation chains
  unsigned long long wb = wbp[0];
  #pragma unroll 2
  for (int t = 0; t < NT; ++t){
    const short* Kt_ = Kib + (size_t)t * 4096;
    const unsigned long long wb_next = (t + 1 < NT) ? wbp[t + 1] : 0;
    short8v kf[8];
    #pragma unroll
    for (int kt = 0; kt < 4; ++kt){
      kf[kt*2+0] = *(const short8v*)(Kt_ + swz(kt * 16 + ll, lh * 8));
      kf[kt*2+1] = *(const short8v*)(Kt_ + swz(kt * 16 + ll, 32 + lh * 8));
    }
    #pragma unroll
    for (int kt = 0; kt < 4; ++kt){
      f32x4 a = (f32x4){0.f, 0.f, 0.f, 0.f};
      a = __builtin_amdgcn_mfma_f32_16x16x32_bf16(kf[kt*2+0], qf[0], a, 0, 0, 0);
      a = __builtin_amdgcn_mfma_f32_16x16x32_bf16(kf[kt*2+1], qf[1], a, 0, 0, 0);
      const unsigned nib = (unsigned)(wb >> (kt * 16 + lh * 4));
      #pragma unroll
      for (int j = 0; j < 4; ++j)
        s4[j] += mask_and(exp2f(a[j] * C_SC), nib, j);
    }
    wb = wb_next;
  }
  float sum = (s4[0] + s4[1]) + (s4[2] + s4[3]);
  sum += __shfl_xor(sum, 16, 64);
  sum += __shfl_xor(sum, 32, 64);
  if (lh == 0) lnl[bh * S_LEN + qrow] = __log2f(sum);
}

// ---------------- PASS 2: probs + O = P.V (contiguous probs stores via LDS transpose) ----------------
__global__ __launch_bounds__(256) void pass_out(
    const short* __restrict__ Qimg, const unsigned long long* __restrict__ bitsg,
    const short* __restrict__ Kimg, const short* __restrict__ Vimg,
    const float* __restrict__ lnl, float* __restrict__ outg, float* __restrict__ probsg)
{
  __shared__ __align__(16) short Pl[4096];        // 2KB per wave, wave-private (bf16 P for PV)
  __shared__ __align__(16) float Pf[4][16][68];   // per-wave fp32 P staging, pad 68 (2-way conflicts)

  const int tid  = threadIdx.x;
  const int wid  = tid >> 6;
  const int lane = tid & 63;
  const int lh   = lane >> 4;
  const int ll   = lane & 15;

  int bh, qt;
  xcd_decode(blockIdx.x, bh, qt);
  const int qrow = qt * 64 + wid * 16 + ll;

  const short* Qib = Qimg + (size_t)bh * S_LEN * 64;
  const short* Kib = Kimg + (size_t)bh * NT * 4096;
  const short* Vib = Vimg + (size_t)bh * NT * 4096;
  float* outb = outg + (size_t)bh * S_LEN * DKC;
  const unsigned long long* wbp = bitsg + (size_t)qrow * NT;
  // contiguous-store row pointer: this lane stores 16B chunks of row (qt*64 + wid*16 + rr*4 + lh)
  float* probsb = probsg + (size_t)bh * S_LEN * S_LEN;

  short8v qf[2];
  qf[0] = *(const short8v*)(Qib + (size_t)qrow * 64 + lh * 8);
  qf[1] = *(const short8v*)(Qib + (size_t)qrow * 64 + 32 + lh * 8);
  const float rlog = lnl[bh * S_LEN + qrow];

  f32x4 o[4];
  #pragma unroll
  for (int dt = 0; dt < 4; ++dt) o[dt] = (f32x4){0.f, 0.f, 0.f, 0.f};

  short* Plw = &Pl[wid * 1024];
  float* Pfw = &Pf[wid][0][0];

  for (int t = 0; t < NT; ++t){
    const unsigned long long wb = wbp[t];
    const short* Kt_ = Kib + (size_t)t * 4096;
    const short* Vt_ = Vib + (size_t)t * 4096;

    #pragma unroll
    for (int h = 0; h < 2; ++h){           // 32-k half: krows h*32 .. h*32+31
      short8v kf[4], vf[4];
      #pragma unroll
      for (int q = 0; q < 2; ++q){
        const int kt = h * 2 + q;
        kf[q*2+0] = *(const short8v*)(Kt_ + swz(kt * 16 + ll, lh * 8));
        kf[q*2+1] = *(const short8v*)(Kt_ + swz(kt * 16 + ll, 32 + lh * 8));
      }
      #pragma unroll
      for (int dt = 0; dt < 4; ++dt)
        vf[dt] = *(const short8v*)(Vt_ + swz(dt * 16 + ll, h * 32 + lh * 8));

      f32x4 acc[2];
      #pragma unroll
      for (int q = 0; q < 2; ++q){
        f32x4 a = (f32x4){0.f, 0.f, 0.f, 0.f};
        a = __builtin_amdgcn_mfma_f32_16x16x32_bf16(kf[q*2+0], qf[0], a, 0, 0, 0);
        a = __builtin_amdgcn_mfma_f32_16x16x32_bf16(kf[q*2+1], qf[1], a, 0, 0, 0);
        acc[q] = a;
      }

      #pragma unroll
      for (int q = 0; q < 2; ++q){
        const int kt = h * 2 + q;
        const unsigned nib = (unsigned)(wb >> (kt * 16 + lh * 4));
        float p[4];
        #pragma unroll
        for (int j = 0; j < 4; ++j)
          p[j] = mask_and(exp2f(fmaf(acc[q][j], C_SC, -rlog)), nib, j);
        f32x4 pv; pv[0]=p[0]; pv[1]=p[1]; pv[2]=p[2]; pv[3]=p[3];
        *(f32x4*)&Pfw[ll * 68 + kt * 16 + lh * 4] = pv;           // fp32 staging (row=own q-row)
        uint2v pk; pk[0] = packbf(p[0], p[1]); pk[1] = packbf(p[2], p[3]);
        *(uint2v*)&Plw[swz(ll, kt * 16 + lh * 4)] = pk;
      }

      const short8v pf = *(const short8v*)&Plw[swz(ll, h * 32 + lh * 8)];
      #pragma unroll
      for (int dt = 0; dt < 4; ++dt)
        o[dt] = __builtin_amdgcn_mfma_f32_16x16x32_bf16(pf, vf[dt], o[dt], 0, 0, 0);
    }

    // contiguous probs stores: each instruction writes 4 rows x 256B-contiguous 16-lane groups
    #pragma unroll
    for (int rr = 0; rr < 4; ++rr){
      const f32x4 pv = *(const f32x4*)&Pfw[(rr * 4 + lh) * 68 + ll * 4];
      __builtin_nontemporal_store(pv,
        (f32x4*)&probsb[(size_t)(qt * 64 + wid * 16 + rr * 4 + lh) * S_LEN + t * 64 + ll * 4]);
    }
  }

  #pragma unroll
  for (int dt = 0; dt < 4; ++dt)
    #pragma unroll
    for (int j = 0; j < 4; ++j)
      __builtin_nontemporal_store(o[dt][j], &outb[(size_t)(qt * 64 + wid * 16 + lh * 4 + j) * DKC + dt * 16 + ll]);
}

// ---------------- fallback: monolithic two-pass with LDS staging ----------------
template<int BITS>
__global__ __launch_bounds__(256) void attn_fb(
    const float* __restrict__ Qg, const float* __restrict__ Kg, const float* __restrict__ Vg,
    const int* __restrict__ maskg, const unsigned long long* __restrict__ bitsg,
    float* __restrict__ outg, float* __restrict__ probsg)
{
  __shared__ __align__(16) short Kl[4096];
  __shared__ __align__(16) short Vt[4096];
  __shared__ __align__(16) short Pl[4096];

  const int tid  = threadIdx.x;
  const int wid  = tid >> 6;
  const int lane = tid & 63;
  const int lh   = lane >> 4;
  const int ll   = lane & 15;

  const int qt    = blockIdx.x & 31;
  const int bh    = blockIdx.x >> 5;
  const int qbase = qt * 64;
  const int qrow  = qbase + wid * 16 + ll;

  const float* Qb = Qg + (size_t)bh * S_LEN * DKC;
  const float* Kb = Kg + (size_t)bh * S_LEN * DKC;
  const float* Vb = Vg + (size_t)bh * S_LEN * DKC;
  float* outb   = outg   + (size_t)bh * S_LEN * DKC;
  float* probsb = probsg + (size_t)bh * S_LEN * S_LEN;

  short8v qf[2];
  #pragma unroll
  for (int h = 0; h < 2; ++h){
    const float4 a = *(const float4*)(Qb + (size_t)qrow * DKC + h * 32 + lh * 8);
    const float4 b = *(const float4*)(Qb + (size_t)qrow * DKC + h * 32 + lh * 8 + 4);
    short8v t;
    t[0]=f2bf(a.x); t[1]=f2bf(a.y); t[2]=f2bf(a.z); t[3]=f2bf(a.w);
    t[4]=f2bf(b.x); t[5]=f2bf(b.y); t[6]=f2bf(b.z); t[7]=f2bf(b.w);
    qf[h] = t;
  }

  float sum = 0.f;
  for (int t = 0; t < NT; ++t){
    __syncthreads();
    stage_rows_bf16(Kl, Kb + (size_t)t * 64 * DKC, tid);
    __syncthreads();
    unsigned long long wb = 0;
    if constexpr (BITS) wb = bitsg[(size_t)qrow * NT + t];
    #pragma unroll
    for (int kt = 0; kt < 4; ++kt){
      const short8v kf0 = *(const short8v*)&Kl[swz(kt * 16 + ll, lh * 8)];
      const short8v kf1 = *(const short8v*)&Kl[swz(kt * 16 + ll, 32 + lh * 8)];
      f32x4 a = (f32x4){0.f, 0.f, 0.f, 0.f};
      a = __builtin_amdgcn_mfma_f32_16x16x32_bf16(kf0, qf[0], a, 0, 0, 0);
      a = __builtin_amdgcn_mfma_f32_16x16x32_bf16(kf1, qf[1], a, 0, 0, 0);
      #pragma unroll
      for (int j = 0; j < 4; ++j){
        const int bi = kt * 16 + lh * 4 + j;
        int keep;
        if constexpr (BITS) keep = (int)((wb >> bi) & 1ull);
        else                keep = maskg[(size_t)qrow * S_LEN + t * 64 + bi] != 0;
        sum += exp2f(keep ? a[j] * C_SC : NEGV);
      }
    }
  }
  sum += __shfl_xor(sum, 16, 64);
  sum += __shfl_xor(sum, 32, 64);
  const float rlog = __log2f(sum);

  f32x4 o[4];
  #pragma unroll
  for (int dt = 0; dt < 4; ++dt) o[dt] = (f32x4){0.f, 0.f, 0.f, 0.f};

  for (int t = 0; t < NT; ++t){
    __syncthreads();
    stage_rows_bf16(Kl, Kb + (size_t)t * 64 * DKC, tid);
    stage_vT_bf16 (Vt, Vb + (size_t)t * 64 * DKC, tid);
    __syncthreads();
    f32x4 acc[4];
    #pragma unroll
    for (int kt = 0; kt < 4; ++kt){
      const short8v kf0 = *(const short8v*)&Kl[swz(kt * 16 + ll, lh * 8)];
      const short8v kf1 = *(const short8v*)&Kl[swz(kt * 16 + ll, 32 + lh * 8)];
      f32x4 a = (f32x4){0.f, 0.f, 0.f, 0.f};
      a = __builtin_amdgcn_mfma_f32_16x16x32_bf16(kf0, qf[0], a, 0, 0, 0);
      a = __builtin_amdgcn_mfma_f32_16x16x32_bf16(kf1, qf[1], a, 0, 0, 0);
      acc[kt] = a;
    }
    unsigned long long wb = 0;
    if constexpr (BITS) wb = bitsg[(size_t)qrow * NT + t];
    #pragma unroll
    for (int kt = 0; kt < 4; ++kt){
      float p[4];
      #pragma unroll
      for (int j = 0; j < 4; ++j){
        const int bi = kt * 16 + lh * 4 + j;
        int keep;
        if constexpr (BITS) keep = (int)((wb >> bi) & 1ull);
        else                keep = maskg[(size_t)qrow * S_LEN + t * 64 + bi] != 0;
        p[j] = exp2f(keep ? fmaf(acc[kt][j], C_SC, -rlog) : NEGV);
      }
      f32x4 pv; pv[0]=p[0]; pv[1]=p[1]; pv[2]=p[2]; pv[3]=p[3];
      __builtin_nontemporal_store(pv, (f32x4*)&probsb[(size_t)qrow * S_LEN + t * 64 + kt * 16 + lh * 4]);
      short4 ps; ps.x=f2bf(p[0]); ps.y=f2bf(p[1]); ps.z=f2bf(p[2]); ps.w=f2bf(p[3]);
      *(short4*)&Pl[wid * 1024 + swz(ll, kt * 16 + lh * 4)] = ps;
    }
    asm volatile("s_waitcnt lgkmcnt(0)" ::: "memory");
    __builtin_amdgcn_sched_barrier(0);
    #pragma unroll
    for (int k32 = 0; k32 < 2; ++k32){
      const short8v pf = *(const short8v*)&Pl[wid * 1024 + swz(ll, k32 * 32 + lh * 8)];
      #pragma unroll
      for (int dt = 0; dt < 4; ++dt){
        const short8v vf = *(const short8v*)&Vt[swz(dt * 16 + ll, k32 * 32 + lh * 8)];
        o[dt] = __builtin_amdgcn_mfma_f32_16x16x32_bf16(pf, vf, o[dt], 0, 0, 0);
      }
    }
  }

  #pragma unroll
  for (int dt = 0; dt < 4; ++dt)
    #pragma unroll
    for (int j = 0; j < 4; ++j)
      __builtin_nontemporal_store(o[dt][j], &outb[(size_t)(qbase + wid * 16 + lh * 4 + j) * DKC + dt * 16 + ll]);
}

extern "C" void kernel_launch(void* const* d_in, const int* in_sizes, int n_in,
                              void* d_out, int out_size, void* d_ws, size_t ws_size,
                              hipStream_t stream) {
  const float* Q    = (const float*)d_in[0];
  const float* K    = (const float*)d_in[1];
  const float* V    = (const float*)d_in[2];
  const int*   mask = (const int*)d_in[3];

  float* out   = (float*)d_out;
  float* probs = out + (size_t)4 * 16 * 2048 * 64;

  const size_t bitsB = (size_t)S_LEN * S_LEN / 8;          // 512 KiB
  const size_t imgB  = (size_t)64 * NT * 4096 * 2;         // 16 MiB each
  const size_t lnlB  = (size_t)64 * S_LEN * 4;             // 512 KiB
  unsigned long long* bits = (unsigned long long*)d_ws;
  short* Kimg = (short*)((char*)d_ws + bitsB);
  short* Vimg = (short*)((char*)d_ws + bitsB + imgB);
  short* Qimg = (short*)((char*)d_ws + bitsB + 2 * imgB);
  float* lnl  = (float*)((char*)d_ws + bitsB + 3 * imgB);

  int mode;
  if      (ws_size >= bitsB + 3 * imgB + lnlB) mode = 2;
  else if (ws_size >= bitsB)                   mode = 1;
  else                                         mode = 0;

  if (mode == 2){
    kvq_convert<<<64 * NT, 256, 0, stream>>>(K, V, Q, mask, bits, Kimg, Vimg, Qimg);
    pass_sum<<<64 * 32, 256, 0, stream>>>(Qimg, bits, Kimg, lnl);
    pass_out<<<64 * 32, 256, 0, stream>>>(Qimg, bits, Kimg, Vimg, lnl, out, probs);
  } else if (mode == 1){
    maskpack_kernel<<<256, 256, 0, stream>>>(mask, bits);
    attn_fb<1><<<64 * 32, 256, 0, stream>>>(Q, K, V, mask, bits, out, probs);
  } else {
    attn_fb<0><<<64 * 32, 256, 0, stream>>>(Q, K, V, mask, bits, out, probs);
  }
}

// Round 10
// 410.691 us; speedup vs baseline: 1.1535x; 1.0084x over previous
//
#include <hip/hip_runtime.h>
#include <hip/hip_bf16.h>

#define S_LEN 2048
#define NT    32
#define DKC   64
#define NEGV  (-1e9f)
// 0.125 * log2(e): folds the 1/sqrt(64) scale and the exp->exp2 conversion
#define C_SC  0.18033688011112042f

typedef __attribute__((ext_vector_type(8))) short short8v;
typedef __attribute__((ext_vector_type(4))) float f32x4;
typedef __attribute__((ext_vector_type(2))) unsigned uint2v;

__device__ __forceinline__ short f2bf(float f){
  unsigned u = __builtin_bit_cast(unsigned, f);
  u += 0x7fffu + ((u >> 16) & 1u);          // RNE to bf16 (images)
  return (short)(u >> 16);
}

// pack two floats -> bf16 pair (round-half-up; P in [0,1], error <= 2^-9 rel)
__device__ __forceinline__ unsigned packbf(float a, float b){
  const unsigned ua = __builtin_bit_cast(unsigned, a) + 0x8000u;
  const unsigned ub = __builtin_bit_cast(unsigned, b) + 0x8000u;
  return (ua >> 16) | (ub & 0xFFFF0000u);
}

// masked value: keep f where bit j of nib is set, else +0.0f (2 VALU: sbfe + and)
__device__ __forceinline__ float mask_and(float f, unsigned nib, int j){
  const int m = __builtin_amdgcn_sbfe(nib, j, 1);      // 0 or 0xFFFFFFFF
  return __builtin_bit_cast(float, m & __builtin_bit_cast(int, f));
}

// swizzled element index for a [rows][64] bf16 tile (128B rows): XOR bits 3-5
__device__ __forceinline__ int swz(int row, int col){
  return (row * 64 + col) ^ ((row & 7) << 3);
}

// chunked XCD decode: all 32 q-tiles (or k-tiles) of a bh on XCD bh&7
__device__ __forceinline__ void xcd_decode(int p, int& bh, int& qt){
  const int xcd = p & 7;
  const int n   = p >> 3;
  bh = ((n >> 5) << 3) | xcd;
  qt = n & 31;
}

// ---------------- fallback staging (no-ws path) ----------------
__device__ __forceinline__ void stage_rows_bf16(short* dst, const float* src, int tid){
  const int r  = tid >> 2;
  const int c0 = (tid & 3) * 16;
  const float* p = src + (size_t)r * DKC + c0;
  float4 a0 = *(const float4*)(p);
  float4 a1 = *(const float4*)(p + 4);
  float4 a2 = *(const float4*)(p + 8);
  float4 a3 = *(const float4*)(p + 12);
  short8v s0, s1;
  s0[0]=f2bf(a0.x); s0[1]=f2bf(a0.y); s0[2]=f2bf(a0.z); s0[3]=f2bf(a0.w);
  s0[4]=f2bf(a1.x); s0[5]=f2bf(a1.y); s0[6]=f2bf(a1.z); s0[7]=f2bf(a1.w);
  s1[0]=f2bf(a2.x); s1[1]=f2bf(a2.y); s1[2]=f2bf(a2.z); s1[3]=f2bf(a2.w);
  s1[4]=f2bf(a3.x); s1[5]=f2bf(a3.y); s1[6]=f2bf(a3.z); s1[7]=f2bf(a3.w);
  *(short8v*)&dst[swz(r, c0)]     = s0;
  *(short8v*)&dst[swz(r, c0 + 8)] = s1;
}

__device__ __forceinline__ void stage_vT_bf16(short* dst, const float* src, int tid){
  const int k  = tid >> 4;
  const int d0 = (tid & 15) * 4;
  #pragma unroll
  for (int i = 0; i < 4; ++i){
    const int kk = k + 16 * i;
    const float4 v = *(const float4*)(src + (size_t)kk * DKC + d0);
    dst[swz(d0 + 0, kk)] = f2bf(v.x);
    dst[swz(d0 + 1, kk)] = f2bf(v.y);
    dst[swz(d0 + 2, kk)] = f2bf(v.z);
    dst[swz(d0 + 3, kk)] = f2bf(v.w);
  }
}

// ---------------- standalone maskpack (mode 1 only) ----------------
__global__ void maskpack_kernel(const int* __restrict__ mask, unsigned long long* __restrict__ bits){
  const int w    = blockIdx.x * 4 + (threadIdx.x >> 6);
  const int lane = threadIdx.x & 63;
  for (int i = 0; i < 64; ++i){
    const size_t word = (size_t)w * 64 + i;
    const int v = mask[word * 64 + lane];
    const unsigned long long b = __ballot(v != 0);
    if (lane == 0) bits[word] = b;
  }
}

// Convert one 64x64 tile: K -> bf16 swizzled [r][d], V -> transposed swizzled [d][k],
// Q -> plain row-major bf16; plus pack 32 mask words per block (8 per wave).
__global__ __launch_bounds__(256) void kvq_convert(
    const float* __restrict__ Kg, const float* __restrict__ Vg, const float* __restrict__ Qg,
    const int* __restrict__ mask, unsigned long long* __restrict__ bits,
    short* __restrict__ Kimg, short* __restrict__ Vimg, short* __restrict__ Qimg){
  __shared__ float Vf[64][65];
  const int tid  = threadIdx.x;
  const int wid  = tid >> 6;
  const int lane = tid & 63;
  int bh, t;
  xcd_decode(blockIdx.x, bh, t);
  const size_t tile = (size_t)bh * NT + t;
  const float* Kb = Kg + tile * (64 * 64);
  const float* Vb = Vg + tile * (64 * 64);
  const float* Qb = Qg + tile * (64 * 64);
  short* Ki = Kimg + tile * 4096;
  short* Vi = Vimg + tile * 4096;
  short* Qi = Qimg + tile * 4096;

  // mask packing: wave gw handles words gw*8 .. gw*8+7
  {
    const int gw = blockIdx.x * 4 + wid;
    #pragma unroll
    for (int i = 0; i < 8; ++i){
      const size_t word = (size_t)gw * 8 + i;
      const int v = mask[word * 64 + lane];
      const unsigned long long b = __ballot(v != 0);
      if (lane == 0) bits[word] = b;
    }
  }

  // K (swizzled) + Q (plain): direct row conversion
  {
    const int r = tid >> 2, c0 = (tid & 3) * 16;
    const float* p = Kb + (size_t)r * 64 + c0;
    float4 a0 = *(const float4*)(p);
    float4 a1 = *(const float4*)(p + 4);
    float4 a2 = *(const float4*)(p + 8);
    float4 a3 = *(const float4*)(p + 12);
    short8v s0, s1;
    s0[0]=f2bf(a0.x); s0[1]=f2bf(a0.y); s0[2]=f2bf(a0.z); s0[3]=f2bf(a0.w);
    s0[4]=f2bf(a1.x); s0[5]=f2bf(a1.y); s0[6]=f2bf(a1.z); s0[7]=f2bf(a1.w);
    s1[0]=f2bf(a2.x); s1[1]=f2bf(a2.y); s1[2]=f2bf(a2.z); s1[3]=f2bf(a2.w);
    s1[4]=f2bf(a3.x); s1[5]=f2bf(a3.y); s1[6]=f2bf(a3.z); s1[7]=f2bf(a3.w);
    *(short8v*)&Ki[swz(r, c0)]     = s0;
    *(short8v*)&Ki[swz(r, c0 + 8)] = s1;

    const float* q = Qb + (size_t)r * 64 + c0;
    float4 b0 = *(const float4*)(q);
    float4 b1 = *(const float4*)(q + 4);
    float4 b2 = *(const float4*)(q + 8);
    float4 b3 = *(const float4*)(q + 12);
    short8v t0, t1;
    t0[0]=f2bf(b0.x); t0[1]=f2bf(b0.y); t0[2]=f2bf(b0.z); t0[3]=f2bf(b0.w);
    t0[4]=f2bf(b1.x); t0[5]=f2bf(b1.y); t0[6]=f2bf(b1.z); t0[7]=f2bf(b1.w);
    t1[0]=f2bf(b2.x); t1[1]=f2bf(b2.y); t1[2]=f2bf(b2.z); t1[3]=f2bf(b2.w);
    t1[4]=f2bf(b3.x); t1[5]=f2bf(b3.y); t1[6]=f2bf(b3.z); t1[7]=f2bf(b3.w);
    *(short8v*)&Qi[r * 64 + c0]     = t0;
    *(short8v*)&Qi[r * 64 + c0 + 8] = t1;
  }
  // V: LDS transpose
  {
    const int k = tid >> 2, c0 = (tid & 3) * 16;
    const float* p = Vb + (size_t)k * 64 + c0;
    float4 a0 = *(const float4*)(p);
    float4 a1 = *(const float4*)(p + 4);
    float4 a2 = *(const float4*)(p + 8);
    float4 a3 = *(const float4*)(p + 12);
    Vf[k][c0+0]=a0.x; Vf[k][c0+1]=a0.y; Vf[k][c0+2]=a0.z; Vf[k][c0+3]=a0.w;
    Vf[k][c0+4]=a1.x; Vf[k][c0+5]=a1.y; Vf[k][c0+6]=a1.z; Vf[k][c0+7]=a1.w;
    Vf[k][c0+8]=a2.x; Vf[k][c0+9]=a2.y; Vf[k][c0+10]=a2.z; Vf[k][c0+11]=a2.w;
    Vf[k][c0+12]=a3.x; Vf[k][c0+13]=a3.y; Vf[k][c0+14]=a3.z; Vf[k][c0+15]=a3.w;
  }
  __syncthreads();
  {
    const int d = tid >> 2, k0 = (tid & 3) * 16;
    short8v s0, s1;
    #pragma unroll
    for (int i = 0; i < 8; ++i) s0[i] = f2bf(Vf[k0 + i][d]);
    #pragma unroll
    for (int i = 0; i < 8; ++i) s1[i] = f2bf(Vf[k0 + 8 + i][d]);
    *(short8v*)&Vi[swz(d, k0)]     = s0;
    *(short8v*)&Vi[swz(d, k0 + 8)] = s1;
  }
}

// ---------------- PASS 1: denominators (log2 of row sums) ----------------
__global__ __launch_bounds__(256) void pass_sum(
    const short* __restrict__ Qimg, const unsigned long long* __restrict__ bitsg,
    const short* __restrict__ Kimg, float* __restrict__ lnl)
{
  const int tid  = threadIdx.x;
  const int wid  = tid >> 6;
  const int lane = tid & 63;
  const int lh   = lane >> 4;
  const int ll   = lane & 15;

  int bh, qt;
  xcd_decode(blockIdx.x, bh, qt);
  const int qrow = qt * 64 + wid * 16 + ll;

  const short* Qib = Qimg + (size_t)bh * S_LEN * 64;
  const short* Kib = Kimg + (size_t)bh * NT * 4096;
  const unsigned long long* wbp = bitsg + (size_t)qrow * NT;

  short8v qf[2];
  qf[0] = *(const short8v*)(Qib + (size_t)qrow * 64 + lh * 8);
  qf[1] = *(const short8v*)(Qib + (size_t)qrow * 64 + 32 + lh * 8);

  float s4[4] = {0.f, 0.f, 0.f, 0.f};      // 4 independent accumulation chains
  unsigned long long wb = wbp[0];
  #pragma unroll 2
  for (int t = 0; t < NT; ++t){
    const short* Kt_ = Kib + (size_t)t * 4096;
    const unsigned long long wb_next = (t + 1 < NT) ? wbp[t + 1] : 0;
    short8v kf[8];
    #pragma unroll
    for (int kt = 0; kt < 4; ++kt){
      kf[kt*2+0] = *(const short8v*)(Kt_ + swz(kt * 16 + ll, lh * 8));
      kf[kt*2+1] = *(const short8v*)(Kt_ + swz(kt * 16 + ll, 32 + lh * 8));
    }
    #pragma unroll
    for (int kt = 0; kt < 4; ++kt){
      f32x4 a = (f32x4){0.f, 0.f, 0.f, 0.f};
      a = __builtin_amdgcn_mfma_f32_16x16x32_bf16(kf[kt*2+0], qf[0], a, 0, 0, 0);
      a = __builtin_amdgcn_mfma_f32_16x16x32_bf16(kf[kt*2+1], qf[1], a, 0, 0, 0);
      const unsigned nib = (unsigned)(wb >> (kt * 16 + lh * 4));
      #pragma unroll
      for (int j = 0; j < 4; ++j)
        s4[j] += mask_and(exp2f(a[j] * C_SC), nib, j);
    }
    wb = wb_next;
  }
  float sum = (s4[0] + s4[1]) + (s4[2] + s4[3]);
  sum += __shfl_xor(sum, 16, 64);
  sum += __shfl_xor(sum, 32, 64);
  if (lh == 0) lnl[bh * S_LEN + qrow] = __log2f(sum);
}

// ---------------- PASS 2: probs + O = P.V ----------------
// Contiguous probs stores via LDS transpose, pipelined one tile late so the
// stores are always YOUNGER than the loads compute waits on (vmcnt in-order).
__global__ __launch_bounds__(256) void pass_out(
    const short* __restrict__ Qimg, const unsigned long long* __restrict__ bitsg,
    const short* __restrict__ Kimg, const short* __restrict__ Vimg,
    const float* __restrict__ lnl, float* __restrict__ outg, float* __restrict__ probsg)
{
  __shared__ __align__(16) short Pl[4096];        // 2KB per wave, wave-private (bf16 P for PV)
  __shared__ __align__(16) float Pf[4][16][68];   // per-wave fp32 P staging

  const int tid  = threadIdx.x;
  const int wid  = tid >> 6;
  const int lane = tid & 63;
  const int lh   = lane >> 4;
  const int ll   = lane & 15;

  int bh, qt;
  xcd_decode(blockIdx.x, bh, qt);
  const int qrow = qt * 64 + wid * 16 + ll;

  const short* Qib = Qimg + (size_t)bh * S_LEN * 64;
  const short* Kib = Kimg + (size_t)bh * NT * 4096;
  const short* Vib = Vimg + (size_t)bh * NT * 4096;
  float* outb = outg + (size_t)bh * S_LEN * DKC;
  const unsigned long long* wbp = bitsg + (size_t)qrow * NT;
  float* probsb = probsg + (size_t)bh * S_LEN * S_LEN;

  short8v qf[2];
  qf[0] = *(const short8v*)(Qib + (size_t)qrow * 64 + lh * 8);
  qf[1] = *(const short8v*)(Qib + (size_t)qrow * 64 + 32 + lh * 8);
  const float rlog = lnl[bh * S_LEN + qrow];

  f32x4 o[4];
  #pragma unroll
  for (int dt = 0; dt < 4; ++dt) o[dt] = (f32x4){0.f, 0.f, 0.f, 0.f};

  short* Plw = &Pl[wid * 1024];
  float* Pfw = &Pf[wid][0][0];

  for (int t = 0; t < NT; ++t){
    const unsigned long long wb = wbp[t];
    const short* Kt_ = Kib + (size_t)t * 4096;
    const short* Vt_ = Vib + (size_t)t * 4096;

    // ---- h=0 loads FIRST (so flush stores below are younger than them) ----
    short8v kf0[4], vf0[4];
    #pragma unroll
    for (int q = 0; q < 2; ++q){
      kf0[q*2+0] = *(const short8v*)(Kt_ + swz(q * 16 + ll, lh * 8));
      kf0[q*2+1] = *(const short8v*)(Kt_ + swz(q * 16 + ll, 32 + lh * 8));
    }
    #pragma unroll
    for (int dt = 0; dt < 4; ++dt)
      vf0[dt] = *(const short8v*)(Vt_ + swz(dt * 16 + ll, lh * 8));

    // ---- flush previous tile's probs (stores get a full tile to retire) ----
    if (t){
      #pragma unroll
      for (int rr = 0; rr < 4; ++rr){
        const f32x4 pv = *(const f32x4*)&Pfw[(rr * 4 + lh) * 68 + ll * 4];
        __builtin_nontemporal_store(pv,
          (f32x4*)&probsb[(size_t)(qt * 64 + wid * 16 + rr * 4 + lh) * S_LEN + (t - 1) * 64 + ll * 4]);
      }
    }

    // ---- h=0 compute ----
    {
      f32x4 acc[2];
      #pragma unroll
      for (int q = 0; q < 2; ++q){
        f32x4 a = (f32x4){0.f, 0.f, 0.f, 0.f};
        a = __builtin_amdgcn_mfma_f32_16x16x32_bf16(kf0[q*2+0], qf[0], a, 0, 0, 0);
        a = __builtin_amdgcn_mfma_f32_16x16x32_bf16(kf0[q*2+1], qf[1], a, 0, 0, 0);
        acc[q] = a;
      }
      #pragma unroll
      for (int q = 0; q < 2; ++q){
        const int kt = q;
        const unsigned nib = (unsigned)(wb >> (kt * 16 + lh * 4));
        float p[4];
        #pragma unroll
        for (int j = 0; j < 4; ++j)
          p[j] = mask_and(exp2f(fmaf(acc[q][j], C_SC, -rlog)), nib, j);
        f32x4 pv; pv[0]=p[0]; pv[1]=p[1]; pv[2]=p[2]; pv[3]=p[3];
        *(f32x4*)&Pfw[ll * 68 + kt * 16 + lh * 4] = pv;
        uint2v pk; pk[0] = packbf(p[0], p[1]); pk[1] = packbf(p[2], p[3]);
        *(uint2v*)&Plw[swz(ll, kt * 16 + lh * 4)] = pk;
      }
      const short8v pf = *(const short8v*)&Plw[swz(ll, lh * 8)];
      #pragma unroll
      for (int dt = 0; dt < 4; ++dt)
        o[dt] = __builtin_amdgcn_mfma_f32_16x16x32_bf16(pf, vf0[dt], o[dt], 0, 0, 0);
    }

    // ---- h=1 ----
    {
      short8v kf1[4], vf1[4];
      #pragma unroll
      for (int q = 0; q < 2; ++q){
        const int kt = 2 + q;
        kf1[q*2+0] = *(const short8v*)(Kt_ + swz(kt * 16 + ll, lh * 8));
        kf1[q*2+1] = *(const short8v*)(Kt_ + swz(kt * 16 + ll, 32 + lh * 8));
      }
      #pragma unroll
      for (int dt = 0; dt < 4; ++dt)
        vf1[dt] = *(const short8v*)(Vt_ + swz(dt * 16 + ll, 32 + lh * 8));

      f32x4 acc[2];
      #pragma unroll
      for (int q = 0; q < 2; ++q){
        f32x4 a = (f32x4){0.f, 0.f, 0.f, 0.f};
        a = __builtin_amdgcn_mfma_f32_16x16x32_bf16(kf1[q*2+0], qf[0], a, 0, 0, 0);
        a = __builtin_amdgcn_mfma_f32_16x16x32_bf16(kf1[q*2+1], qf[1], a, 0, 0, 0);
        acc[q] = a;
      }
      #pragma unroll
      for (int q = 0; q < 2; ++q){
        const int kt = 2 + q;
        const unsigned nib = (unsigned)(wb >> (kt * 16 + lh * 4));
        float p[4];
        #pragma unroll
        for (int j = 0; j < 4; ++j)
          p[j] = mask_and(exp2f(fmaf(acc[q][j], C_SC, -rlog)), nib, j);
        f32x4 pv; pv[0]=p[0]; pv[1]=p[1]; pv[2]=p[2]; pv[3]=p[3];
        *(f32x4*)&Pfw[ll * 68 + kt * 16 + lh * 4] = pv;
        uint2v pk; pk[0] = packbf(p[0], p[1]); pk[1] = packbf(p[2], p[3]);
        *(uint2v*)&Plw[swz(ll, kt * 16 + lh * 4)] = pk;
      }
      const short8v pf = *(const short8v*)&Plw[swz(ll, 32 + lh * 8)];
      #pragma unroll
      for (int dt = 0; dt < 4; ++dt)
        o[dt] = __builtin_amdgcn_mfma_f32_16x16x32_bf16(pf, vf1[dt], o[dt], 0, 0, 0);
    }
  }

  // final flush (tile NT-1)
  #pragma unroll
  for (int rr = 0; rr < 4; ++rr){
    const f32x4 pv = *(const f32x4*)&Pfw[(rr * 4 + lh) * 68 + ll * 4];
    __builtin_nontemporal_store(pv,
      (f32x4*)&probsb[(size_t)(qt * 64 + wid * 16 + rr * 4 + lh) * S_LEN + (NT - 1) * 64 + ll * 4]);
  }

  #pragma unroll
  for (int dt = 0; dt < 4; ++dt)
    #pragma unroll
    for (int j = 0; j < 4; ++j)
      __builtin_nontemporal_store(o[dt][j], &outb[(size_t)(qt * 64 + wid * 16 + lh * 4 + j) * DKC + dt * 16 + ll]);
}

// ---------------- fallback: monolithic two-pass with LDS staging ----------------
template<int BITS>
__global__ __launch_bounds__(256) void attn_fb(
    const float* __restrict__ Qg, const float* __restrict__ Kg, const float* __restrict__ Vg,
    const int* __restrict__ maskg, const unsigned long long* __restrict__ bitsg,
    float* __restrict__ outg, float* __restrict__ probsg)
{
  __shared__ __align__(16) short Kl[4096];
  __shared__ __align__(16) short Vt[4096];
  __shared__ __align__(16) short Pl[4096];

  const int tid  = threadIdx.x;
  const int wid  = tid >> 6;
  const int lane = tid & 63;
  const int lh   = lane >> 4;
  const int ll   = lane & 15;

  const int qt    = blockIdx.x & 31;
  const int bh    = blockIdx.x >> 5;
  const int qbase = qt * 64;
  const int qrow  = qbase + wid * 16 + ll;

  const float* Qb = Qg + (size_t)bh * S_LEN * DKC;
  const float* Kb = Kg + (size_t)bh * S_LEN * DKC;
  const float* Vb = Vg + (size_t)bh * S_LEN * DKC;
  float* outb   = outg   + (size_t)bh * S_LEN * DKC;
  float* probsb = probsg + (size_t)bh * S_LEN * S_LEN;

  short8v qf[2];
  #pragma unroll
  for (int h = 0; h < 2; ++h){
    const float4 a = *(const float4*)(Qb + (size_t)qrow * DKC + h * 32 + lh * 8);
    const float4 b = *(const float4*)(Qb + (size_t)qrow * DKC + h * 32 + lh * 8 + 4);
    short8v t;
    t[0]=f2bf(a.x); t[1]=f2bf(a.y); t[2]=f2bf(a.z); t[3]=f2bf(a.w);
    t[4]=f2bf(b.x); t[5]=f2bf(b.y); t[6]=f2bf(b.z); t[7]=f2bf(b.w);
    qf[h] = t;
  }

  float sum = 0.f;
  for (int t = 0; t < NT; ++t){
    __syncthreads();
    stage_rows_bf16(Kl, Kb + (size_t)t * 64 * DKC, tid);
    __syncthreads();
    unsigned long long wb = 0;
    if constexpr (BITS) wb = bitsg[(size_t)qrow * NT + t];
    #pragma unroll
    for (int kt = 0; kt < 4; ++kt){
      const short8v kf0 = *(const short8v*)&Kl[swz(kt * 16 + ll, lh * 8)];
      const short8v kf1 = *(const short8v*)&Kl[swz(kt * 16 + ll, 32 + lh * 8)];
      f32x4 a = (f32x4){0.f, 0.f, 0.f, 0.f};
      a = __builtin_amdgcn_mfma_f32_16x16x32_bf16(kf0, qf[0], a, 0, 0, 0);
      a = __builtin_amdgcn_mfma_f32_16x16x32_bf16(kf1, qf[1], a, 0, 0, 0);
      #pragma unroll
      for (int j = 0; j < 4; ++j){
        const int bi = kt * 16 + lh * 4 + j;
        int keep;
        if constexpr (BITS) keep = (int)((wb >> bi) & 1ull);
        else                keep = maskg[(size_t)qrow * S_LEN + t * 64 + bi] != 0;
        sum += exp2f(keep ? a[j] * C_SC : NEGV);
      }
    }
  }
  sum += __shfl_xor(sum, 16, 64);
  sum += __shfl_xor(sum, 32, 64);
  const float rlog = __log2f(sum);

  f32x4 o[4];
  #pragma unroll
  for (int dt = 0; dt < 4; ++dt) o[dt] = (f32x4){0.f, 0.f, 0.f, 0.f};

  for (int t = 0; t < NT; ++t){
    __syncthreads();
    stage_rows_bf16(Kl, Kb + (size_t)t * 64 * DKC, tid);
    stage_vT_bf16 (Vt, Vb + (size_t)t * 64 * DKC, tid);
    __syncthreads();
    f32x4 acc[4];
    #pragma unroll
    for (int kt = 0; kt < 4; ++kt){
      const short8v kf0 = *(const short8v*)&Kl[swz(kt * 16 + ll, lh * 8)];
      const short8v kf1 = *(const short8v*)&Kl[swz(kt * 16 + ll, 32 + lh * 8)];
      f32x4 a = (f32x4){0.f, 0.f, 0.f, 0.f};
      a = __builtin_amdgcn_mfma_f32_16x16x32_bf16(kf0, qf[0], a, 0, 0, 0);
      a = __builtin_amdgcn_mfma_f32_16x16x32_bf16(kf1, qf[1], a, 0, 0, 0);
      acc[kt] = a;
    }
    unsigned long long wb = 0;
    if constexpr (BITS) wb = bitsg[(size_t)qrow * NT + t];
    #pragma unroll
    for (int kt = 0; kt < 4; ++kt){
      float p[4];
      #pragma unroll
      for (int j = 0; j < 4; ++j){
        const int bi = kt * 16 + lh * 4 + j;
        int keep;
        if constexpr (BITS) keep = (int)((wb >> bi) & 1ull);
        else                keep = maskg[(size_t)qrow * S_LEN + t * 64 + bi] != 0;
        p[j] = exp2f(keep ? fmaf(acc[kt][j], C_SC, -rlog) : NEGV);
      }
      f32x4 pv; pv[0]=p[0]; pv[1]=p[1]; pv[2]=p[2]; pv[3]=p[3];
      __builtin_nontemporal_store(pv, (f32x4*)&probsb[(size_t)qrow * S_LEN + t * 64 + kt * 16 + lh * 4]);
      short4 ps; ps.x=f2bf(p[0]); ps.y=f2bf(p[1]); ps.z=f2bf(p[2]); ps.w=f2bf(p[3]);
      *(short4*)&Pl[wid * 1024 + swz(ll, kt * 16 + lh * 4)] = ps;
    }
    asm volatile("s_waitcnt lgkmcnt(0)" ::: "memory");
    __builtin_amdgcn_sched_barrier(0);
    #pragma unroll
    for (int k32 = 0; k32 < 2; ++k32){
      const short8v pf = *(const short8v*)&Pl[wid * 1024 + swz(ll, k32 * 32 + lh * 8)];
      #pragma unroll
      for (int dt = 0; dt < 4; ++dt){
        const short8v vf = *(const short8v*)&Vt[swz(dt * 16 + ll, k32 * 32 + lh * 8)];
        o[dt] = __builtin_amdgcn_mfma_f32_16x16x32_bf16(pf, vf, o[dt], 0, 0, 0);
      }
    }
  }

  #pragma unroll
  for (int dt = 0; dt < 4; ++dt)
    #pragma unroll
    for (int j = 0; j < 4; ++j)
      __builtin_nontemporal_store(o[dt][j], &outb[(size_t)(qbase + wid * 16 + lh * 4 + j) * DKC + dt * 16 + ll]);
}

extern "C" void kernel_launch(void* const* d_in, const int* in_sizes, int n_in,
                              void* d_out, int out_size, void* d_ws, size_t ws_size,
                              hipStream_t stream) {
  const float* Q    = (const float*)d_in[0];
  const float* K    = (const float*)d_in[1];
  const float* V    = (const float*)d_in[2];
  const int*   mask = (const int*)d_in[3];

  float* out   = (float*)d_out;
  float* probs = out + (size_t)4 * 16 * 2048 * 64;

  const size_t bitsB = (size_t)S_LEN * S_LEN / 8;          // 512 KiB
  const size_t imgB  = (size_t)64 * NT * 4096 * 2;         // 16 MiB each
  const size_t lnlB  = (size_t)64 * S_LEN * 4;             // 512 KiB
  unsigned long long* bits = (unsigned long long*)d_ws;
  short* Kimg = (short*)((char*)d_ws + bitsB);
  short* Vimg = (short*)((char*)d_ws + bitsB + imgB);
  short* Qimg = (short*)((char*)d_ws + bitsB + 2 * imgB);
  float* lnl  = (float*)((char*)d_ws + bitsB + 3 * imgB);

  int mode;
  if      (ws_size >= bitsB + 3 * imgB + lnlB) mode = 2;
  else if (ws_size >= bitsB)                   mode = 1;
  else                                         mode = 0;

  if (mode == 2){
    kvq_convert<<<64 * NT, 256, 0, stream>>>(K, V, Q, mask, bits, Kimg, Vimg, Qimg);
    pass_sum<<<64 * 32, 256, 0, stream>>>(Qimg, bits, Kimg, lnl);
    pass_out<<<64 * 32, 256, 0, stream>>>(Qimg, bits, Kimg, Vimg, lnl, out, probs);
  } else if (mode == 1){
    maskpack_kernel<<<256, 256, 0, stream>>>(mask, bits);
    attn_fb<1><<<64 * 32, 256, 0, stream>>>(Q, K, V, mask, bits, out, probs);
  } else {
    attn_fb<0><<<64 * 32, 256, 0, stream>>>(Q, K, V, mask, bits, out, probs);
  }
}

// Round 11
// 408.132 us; speedup vs baseline: 1.1607x; 1.0063x over previous
//
#include <hip/hip_runtime.h>
#include <hip/hip_bf16.h>

#define S_LEN 2048
#define NT    32
#define DKC   64
#define NEGV  (-1e9f)
// 0.125 * log2(e): folds the 1/sqrt(64) scale and the exp->exp2 conversion
#define C_SC  0.18033688011112042f

typedef __attribute__((ext_vector_type(8))) short short8v;
typedef __attribute__((ext_vector_type(4))) float f32x4;
typedef __attribute__((ext_vector_type(2))) unsigned uint2v;

__device__ __forceinline__ short f2bf(float f){
  unsigned u = __builtin_bit_cast(unsigned, f);
  u += 0x7fffu + ((u >> 16) & 1u);          // RNE to bf16 (images)
  return (short)(u >> 16);
}

// pack two floats -> bf16 pair (round-half-up; P in [0,1], error <= 2^-9 rel)
__device__ __forceinline__ unsigned packbf(float a, float b){
  const unsigned ua = __builtin_bit_cast(unsigned, a) + 0x8000u;
  const unsigned ub = __builtin_bit_cast(unsigned, b) + 0x8000u;
  return (ua >> 16) | (ub & 0xFFFF0000u);
}

// masked value: keep f where bit j of nib is set, else +0.0f (2 VALU: sbfe + and)
__device__ __forceinline__ float mask_and(float f, unsigned nib, int j){
  const int m = __builtin_amdgcn_sbfe(nib, j, 1);      // 0 or 0xFFFFFFFF
  return __builtin_bit_cast(float, m & __builtin_bit_cast(int, f));
}

// swizzled element index for a [rows][64] bf16 tile (128B rows): XOR bits 3-5
__device__ __forceinline__ int swz(int row, int col){
  return (row * 64 + col) ^ ((row & 7) << 3);
}

// chunked XCD decode: all 32 q-tiles (or k-tiles) of a bh on XCD bh&7
__device__ __forceinline__ void xcd_decode(int p, int& bh, int& qt){
  const int xcd = p & 7;
  const int n   = p >> 3;
  bh = ((n >> 5) << 3) | xcd;
  qt = n & 31;
}

// ---------------- fallback staging (no-ws path) ----------------
__device__ __forceinline__ void stage_rows_bf16(short* dst, const float* src, int tid){
  const int r  = tid >> 2;
  const int c0 = (tid & 3) * 16;
  const float* p = src + (size_t)r * DKC + c0;
  float4 a0 = *(const float4*)(p);
  float4 a1 = *(const float4*)(p + 4);
  float4 a2 = *(const float4*)(p + 8);
  float4 a3 = *(const float4*)(p + 12);
  short8v s0, s1;
  s0[0]=f2bf(a0.x); s0[1]=f2bf(a0.y); s0[2]=f2bf(a0.z); s0[3]=f2bf(a0.w);
  s0[4]=f2bf(a1.x); s0[5]=f2bf(a1.y); s0[6]=f2bf(a1.z); s0[7]=f2bf(a1.w);
  s1[0]=f2bf(a2.x); s1[1]=f2bf(a2.y); s1[2]=f2bf(a2.z); s1[3]=f2bf(a2.w);
  s1[4]=f2bf(a3.x); s1[5]=f2bf(a3.y); s1[6]=f2bf(a3.z); s1[7]=f2bf(a3.w);
  *(short8v*)&dst[swz(r, c0)]     = s0;
  *(short8v*)&dst[swz(r, c0 + 8)] = s1;
}

__device__ __forceinline__ void stage_vT_bf16(short* dst, const float* src, int tid){
  const int k  = tid >> 4;
  const int d0 = (tid & 15) * 4;
  #pragma unroll
  for (int i = 0; i < 4; ++i){
    const int kk = k + 16 * i;
    const float4 v = *(const float4*)(src + (size_t)kk * DKC + d0);
    dst[swz(d0 + 0, kk)] = f2bf(v.x);
    dst[swz(d0 + 1, kk)] = f2bf(v.y);
    dst[swz(d0 + 2, kk)] = f2bf(v.z);
    dst[swz(d0 + 3, kk)] = f2bf(v.w);
  }
}

// ---------------- standalone maskpack (mode 1 only) ----------------
__global__ void maskpack_kernel(const int* __restrict__ mask, unsigned long long* __restrict__ bits){
  const int w    = blockIdx.x * 4 + (threadIdx.x >> 6);
  const int lane = threadIdx.x & 63;
  for (int i = 0; i < 64; ++i){
    const size_t word = (size_t)w * 64 + i;
    const int v = mask[word * 64 + lane];
    const unsigned long long b = __ballot(v != 0);
    if (lane == 0) bits[word] = b;
  }
}

// Convert one 64x64 tile: K -> bf16 swizzled [r][d], V -> transposed swizzled [d][k],
// Q -> plain row-major bf16; plus pack 32 mask words per block (8 per wave).
__global__ __launch_bounds__(256) void kvq_convert(
    const float* __restrict__ Kg, const float* __restrict__ Vg, const float* __restrict__ Qg,
    const int* __restrict__ mask, unsigned long long* __restrict__ bits,
    short* __restrict__ Kimg, short* __restrict__ Vimg, short* __restrict__ Qimg){
  __shared__ float Vf[64][65];
  const int tid  = threadIdx.x;
  const int wid  = tid >> 6;
  const int lane = tid & 63;
  int bh, t;
  xcd_decode(blockIdx.x, bh, t);
  const size_t tile = (size_t)bh * NT + t;
  const float* Kb = Kg + tile * (64 * 64);
  const float* Vb = Vg + tile * (64 * 64);
  const float* Qb = Qg + tile * (64 * 64);
  short* Ki = Kimg + tile * 4096;
  short* Vi = Vimg + tile * 4096;
  short* Qi = Qimg + tile * 4096;

  // mask packing: wave gw handles words gw*8 .. gw*8+7
  {
    const int gw = blockIdx.x * 4 + wid;
    #pragma unroll
    for (int i = 0; i < 8; ++i){
      const size_t word = (size_t)gw * 8 + i;
      const int v = mask[word * 64 + lane];
      const unsigned long long b = __ballot(v != 0);
      if (lane == 0) bits[word] = b;
    }
  }

  // K (swizzled) + Q (plain): direct row conversion
  {
    const int r = tid >> 2, c0 = (tid & 3) * 16;
    const float* p = Kb + (size_t)r * 64 + c0;
    float4 a0 = *(const float4*)(p);
    float4 a1 = *(const float4*)(p + 4);
    float4 a2 = *(const float4*)(p + 8);
    float4 a3 = *(const float4*)(p + 12);
    short8v s0, s1;
    s0[0]=f2bf(a0.x); s0[1]=f2bf(a0.y); s0[2]=f2bf(a0.z); s0[3]=f2bf(a0.w);
    s0[4]=f2bf(a1.x); s0[5]=f2bf(a1.y); s0[6]=f2bf(a1.z); s0[7]=f2bf(a1.w);
    s1[0]=f2bf(a2.x); s1[1]=f2bf(a2.y); s1[2]=f2bf(a2.z); s1[3]=f2bf(a2.w);
    s1[4]=f2bf(a3.x); s1[5]=f2bf(a3.y); s1[6]=f2bf(a3.z); s1[7]=f2bf(a3.w);
    *(short8v*)&Ki[swz(r, c0)]     = s0;
    *(short8v*)&Ki[swz(r, c0 + 8)] = s1;

    const float* q = Qb + (size_t)r * 64 + c0;
    float4 b0 = *(const float4*)(q);
    float4 b1 = *(const float4*)(q + 4);
    float4 b2 = *(const float4*)(q + 8);
    float4 b3 = *(const float4*)(q + 12);
    short8v t0, t1;
    t0[0]=f2bf(b0.x); t0[1]=f2bf(b0.y); t0[2]=f2bf(b0.z); t0[3]=f2bf(b0.w);
    t0[4]=f2bf(b1.x); t0[5]=f2bf(b1.y); t0[6]=f2bf(b1.z); t0[7]=f2bf(b1.w);
    t1[0]=f2bf(b2.x); t1[1]=f2bf(b2.y); t1[2]=f2bf(b2.z); t1[3]=f2bf(b2.w);
    t1[4]=f2bf(b3.x); t1[5]=f2bf(b3.y); t1[6]=f2bf(b3.z); t1[7]=f2bf(b3.w);
    *(short8v*)&Qi[r * 64 + c0]     = t0;
    *(short8v*)&Qi[r * 64 + c0 + 8] = t1;
  }
  // V: LDS transpose
  {
    const int k = tid >> 2, c0 = (tid & 3) * 16;
    const float* p = Vb + (size_t)k * 64 + c0;
    float4 a0 = *(const float4*)(p);
    float4 a1 = *(const float4*)(p + 4);
    float4 a2 = *(const float4*)(p + 8);
    float4 a3 = *(const float4*)(p + 12);
    Vf[k][c0+0]=a0.x; Vf[k][c0+1]=a0.y; Vf[k][c0+2]=a0.z; Vf[k][c0+3]=a0.w;
    Vf[k][c0+4]=a1.x; Vf[k][c0+5]=a1.y; Vf[k][c0+6]=a1.z; Vf[k][c0+7]=a1.w;
    Vf[k][c0+8]=a2.x; Vf[k][c0+9]=a2.y; Vf[k][c0+10]=a2.z; Vf[k][c0+11]=a2.w;
    Vf[k][c0+12]=a3.x; Vf[k][c0+13]=a3.y; Vf[k][c0+14]=a3.z; Vf[k][c0+15]=a3.w;
  }
  __syncthreads();
  {
    const int d = tid >> 2, k0 = (tid & 3) * 16;
    short8v s0, s1;
    #pragma unroll
    for (int i = 0; i < 8; ++i) s0[i] = f2bf(Vf[k0 + i][d]);
    #pragma unroll
    for (int i = 0; i < 8; ++i) s1[i] = f2bf(Vf[k0 + 8 + i][d]);
    *(short8v*)&Vi[swz(d, k0)]     = s0;
    *(short8v*)&Vi[swz(d, k0 + 8)] = s1;
  }
}

// ---------------- FUSED: phase 1 row sums (lean) + phase 2 probs/PV ----------------
__global__ __launch_bounds__(256) void attn_f(
    const short* __restrict__ Qimg, const unsigned long long* __restrict__ bitsg,
    const short* __restrict__ Kimg, const short* __restrict__ Vimg,
    float* __restrict__ outg, float* __restrict__ probsg)
{
  __shared__ __align__(16) short Pl[4096];        // 2KB per wave, wave-private (bf16 P for PV)
  __shared__ __align__(16) float Pf[4][16][68];   // per-wave fp32 P staging

  const int tid  = threadIdx.x;
  const int wid  = tid >> 6;
  const int lane = tid & 63;
  const int lh   = lane >> 4;
  const int ll   = lane & 15;

  int bh, qt;
  xcd_decode(blockIdx.x, bh, qt);
  const int qrow = qt * 64 + wid * 16 + ll;

  const short* Qib = Qimg + (size_t)bh * S_LEN * 64;
  const short* Kib = Kimg + (size_t)bh * NT * 4096;
  const short* Vib = Vimg + (size_t)bh * NT * 4096;
  float* outb = outg + (size_t)bh * S_LEN * DKC;
  const unsigned long long* wbp = bitsg + (size_t)qrow * NT;
  float* probsb = probsg + (size_t)bh * S_LEN * S_LEN;

  short8v qf[2];
  qf[0] = *(const short8v*)(Qib + (size_t)qrow * 64 + lh * 8);
  qf[1] = *(const short8v*)(Qib + (size_t)qrow * 64 + 32 + lh * 8);

  // ===== phase 1: row sums (lean register footprint) =====
  float s4[4] = {0.f, 0.f, 0.f, 0.f};
  {
    unsigned long long wb = wbp[0];
    #pragma unroll 2
    for (int t = 0; t < NT; ++t){
      const short* Kt_ = Kib + (size_t)t * 4096;
      const unsigned long long wb_next = (t + 1 < NT) ? wbp[t + 1] : 0;
      short8v kf[8];
      #pragma unroll
      for (int kt = 0; kt < 4; ++kt){
        kf[kt*2+0] = *(const short8v*)(Kt_ + swz(kt * 16 + ll, lh * 8));
        kf[kt*2+1] = *(const short8v*)(Kt_ + swz(kt * 16 + ll, 32 + lh * 8));
      }
      #pragma unroll
      for (int kt = 0; kt < 4; ++kt){
        f32x4 a = (f32x4){0.f, 0.f, 0.f, 0.f};
        a = __builtin_amdgcn_mfma_f32_16x16x32_bf16(kf[kt*2+0], qf[0], a, 0, 0, 0);
        a = __builtin_amdgcn_mfma_f32_16x16x32_bf16(kf[kt*2+1], qf[1], a, 0, 0, 0);
        const unsigned nib = (unsigned)(wb >> (kt * 16 + lh * 4));
        #pragma unroll
        for (int j = 0; j < 4; ++j)
          s4[j] += mask_and(exp2f(a[j] * C_SC), nib, j);
      }
      wb = wb_next;
    }
  }
  float sum = (s4[0] + s4[1]) + (s4[2] + s4[3]);
  sum += __shfl_xor(sum, 16, 64);
  sum += __shfl_xor(sum, 32, 64);
  const float rlog = __log2f(sum);     // stays in-register: no lnl round-trip

  // ===== phase 2: probs + O = P.V (R9/R10 proven body) =====
  f32x4 o[4];
  #pragma unroll
  for (int dt = 0; dt < 4; ++dt) o[dt] = (f32x4){0.f, 0.f, 0.f, 0.f};

  short* Plw = &Pl[wid * 1024];
  float* Pfw = &Pf[wid][0][0];

  for (int t = 0; t < NT; ++t){
    const unsigned long long wb = wbp[t];
    const short* Kt_ = Kib + (size_t)t * 4096;
    const short* Vt_ = Vib + (size_t)t * 4096;

    // ---- h=0 loads FIRST (so flush stores below are younger than them) ----
    short8v kf0[4], vf0[4];
    #pragma unroll
    for (int q = 0; q < 2; ++q){
      kf0[q*2+0] = *(const short8v*)(Kt_ + swz(q * 16 + ll, lh * 8));
      kf0[q*2+1] = *(const short8v*)(Kt_ + swz(q * 16 + ll, 32 + lh * 8));
    }
    #pragma unroll
    for (int dt = 0; dt < 4; ++dt)
      vf0[dt] = *(const short8v*)(Vt_ + swz(dt * 16 + ll, lh * 8));

    // ---- flush previous tile's probs ----
    if (t){
      #pragma unroll
      for (int rr = 0; rr < 4; ++rr){
        const f32x4 pv = *(const f32x4*)&Pfw[(rr * 4 + lh) * 68 + ll * 4];
        __builtin_nontemporal_store(pv,
          (f32x4*)&probsb[(size_t)(qt * 64 + wid * 16 + rr * 4 + lh) * S_LEN + (t - 1) * 64 + ll * 4]);
      }
    }

    // ---- h=0 compute ----
    {
      f32x4 acc[2];
      #pragma unroll
      for (int q = 0; q < 2; ++q){
        f32x4 a = (f32x4){0.f, 0.f, 0.f, 0.f};
        a = __builtin_amdgcn_mfma_f32_16x16x32_bf16(kf0[q*2+0], qf[0], a, 0, 0, 0);
        a = __builtin_amdgcn_mfma_f32_16x16x32_bf16(kf0[q*2+1], qf[1], a, 0, 0, 0);
        acc[q] = a;
      }
      #pragma unroll
      for (int q = 0; q < 2; ++q){
        const int kt = q;
        const unsigned nib = (unsigned)(wb >> (kt * 16 + lh * 4));
        float p[4];
        #pragma unroll
        for (int j = 0; j < 4; ++j)
          p[j] = mask_and(exp2f(fmaf(acc[q][j], C_SC, -rlog)), nib, j);
        f32x4 pv; pv[0]=p[0]; pv[1]=p[1]; pv[2]=p[2]; pv[3]=p[3];
        *(f32x4*)&Pfw[ll * 68 + kt * 16 + lh * 4] = pv;
        uint2v pk; pk[0] = packbf(p[0], p[1]); pk[1] = packbf(p[2], p[3]);
        *(uint2v*)&Plw[swz(ll, kt * 16 + lh * 4)] = pk;
      }
      const short8v pf = *(const short8v*)&Plw[swz(ll, lh * 8)];
      #pragma unroll
      for (int dt = 0; dt < 4; ++dt)
        o[dt] = __builtin_amdgcn_mfma_f32_16x16x32_bf16(pf, vf0[dt], o[dt], 0, 0, 0);
    }

    // ---- h=1 ----
    {
      short8v kf1[4], vf1[4];
      #pragma unroll
      for (int q = 0; q < 2; ++q){
        const int kt = 2 + q;
        kf1[q*2+0] = *(const short8v*)(Kt_ + swz(kt * 16 + ll, lh * 8));
        kf1[q*2+1] = *(const short8v*)(Kt_ + swz(kt * 16 + ll, 32 + lh * 8));
      }
      #pragma unroll
      for (int dt = 0; dt < 4; ++dt)
        vf1[dt] = *(const short8v*)(Vt_ + swz(dt * 16 + ll, 32 + lh * 8));

      f32x4 acc[2];
      #pragma unroll
      for (int q = 0; q < 2; ++q){
        f32x4 a = (f32x4){0.f, 0.f, 0.f, 0.f};
        a = __builtin_amdgcn_mfma_f32_16x16x32_bf16(kf1[q*2+0], qf[0], a, 0, 0, 0);
        a = __builtin_amdgcn_mfma_f32_16x16x32_bf16(kf1[q*2+1], qf[1], a, 0, 0, 0);
        acc[q] = a;
      }
      #pragma unroll
      for (int q = 0; q < 2; ++q){
        const int kt = 2 + q;
        const unsigned nib = (unsigned)(wb >> (kt * 16 + lh * 4));
        float p[4];
        #pragma unroll
        for (int j = 0; j < 4; ++j)
          p[j] = mask_and(exp2f(fmaf(acc[q][j], C_SC, -rlog)), nib, j);
        f32x4 pv; pv[0]=p[0]; pv[1]=p[1]; pv[2]=p[2]; pv[3]=p[3];
        *(f32x4*)&Pfw[ll * 68 + kt * 16 + lh * 4] = pv;
        uint2v pk; pk[0] = packbf(p[0], p[1]); pk[1] = packbf(p[2], p[3]);
        *(uint2v*)&Plw[swz(ll, kt * 16 + lh * 4)] = pk;
      }
      const short8v pf = *(const short8v*)&Plw[swz(ll, 32 + lh * 8)];
      #pragma unroll
      for (int dt = 0; dt < 4; ++dt)
        o[dt] = __builtin_amdgcn_mfma_f32_16x16x32_bf16(pf, vf1[dt], o[dt], 0, 0, 0);
    }
  }

  // final flush (tile NT-1)
  #pragma unroll
  for (int rr = 0; rr < 4; ++rr){
    const f32x4 pv = *(const f32x4*)&Pfw[(rr * 4 + lh) * 68 + ll * 4];
    __builtin_nontemporal_store(pv,
      (f32x4*)&probsb[(size_t)(qt * 64 + wid * 16 + rr * 4 + lh) * S_LEN + (NT - 1) * 64 + ll * 4]);
  }

  #pragma unroll
  for (int dt = 0; dt < 4; ++dt)
    #pragma unroll
    for (int j = 0; j < 4; ++j)
      __builtin_nontemporal_store(o[dt][j], &outb[(size_t)(qt * 64 + wid * 16 + lh * 4 + j) * DKC + dt * 16 + ll]);
}

// ---------------- fallback: monolithic two-pass with LDS staging ----------------
template<int BITS>
__global__ __launch_bounds__(256) void attn_fb(
    const float* __restrict__ Qg, const float* __restrict__ Kg, const float* __restrict__ Vg,
    const int* __restrict__ maskg, const unsigned long long* __restrict__ bitsg,
    float* __restrict__ outg, float* __restrict__ probsg)
{
  __shared__ __align__(16) short Kl[4096];
  __shared__ __align__(16) short Vt[4096];
  __shared__ __align__(16) short Pl[4096];

  const int tid  = threadIdx.x;
  const int wid  = tid >> 6;
  const int lane = tid & 63;
  const int lh   = lane >> 4;
  const int ll   = lane & 15;

  const int qt    = blockIdx.x & 31;
  const int bh    = blockIdx.x >> 5;
  const int qbase = qt * 64;
  const int qrow  = qbase + wid * 16 + ll;

  const float* Qb = Qg + (size_t)bh * S_LEN * DKC;
  const float* Kb = Kg + (size_t)bh * S_LEN * DKC;
  const float* Vb = Vg + (size_t)bh * S_LEN * DKC;
  float* outb   = outg   + (size_t)bh * S_LEN * DKC;
  float* probsb = probsg + (size_t)bh * S_LEN * S_LEN;

  short8v qf[2];
  #pragma unroll
  for (int h = 0; h < 2; ++h){
    const float4 a = *(const float4*)(Qb + (size_t)qrow * DKC + h * 32 + lh * 8);
    const float4 b = *(const float4*)(Qb + (size_t)qrow * DKC + h * 32 + lh * 8 + 4);
    short8v t;
    t[0]=f2bf(a.x); t[1]=f2bf(a.y); t[2]=f2bf(a.z); t[3]=f2bf(a.w);
    t[4]=f2bf(b.x); t[5]=f2bf(b.y); t[6]=f2bf(b.z); t[7]=f2bf(b.w);
    qf[h] = t;
  }

  float sum = 0.f;
  for (int t = 0; t < NT; ++t){
    __syncthreads();
    stage_rows_bf16(Kl, Kb + (size_t)t * 64 * DKC, tid);
    __syncthreads();
    unsigned long long wb = 0;
    if constexpr (BITS) wb = bitsg[(size_t)qrow * NT + t];
    #pragma unroll
    for (int kt = 0; kt < 4; ++kt){
      const short8v kf0 = *(const short8v*)&Kl[swz(kt * 16 + ll, lh * 8)];
      const short8v kf1 = *(const short8v*)&Kl[swz(kt * 16 + ll, 32 + lh * 8)];
      f32x4 a = (f32x4){0.f, 0.f, 0.f, 0.f};
      a = __builtin_amdgcn_mfma_f32_16x16x32_bf16(kf0, qf[0], a, 0, 0, 0);
      a = __builtin_amdgcn_mfma_f32_16x16x32_bf16(kf1, qf[1], a, 0, 0, 0);
      #pragma unroll
      for (int j = 0; j < 4; ++j){
        const int bi = kt * 16 + lh * 4 + j;
        int keep;
        if constexpr (BITS) keep = (int)((wb >> bi) & 1ull);
        else                keep = maskg[(size_t)qrow * S_LEN + t * 64 + bi] != 0;
        sum += exp2f(keep ? a[j] * C_SC : NEGV);
      }
    }
  }
  sum += __shfl_xor(sum, 16, 64);
  sum += __shfl_xor(sum, 32, 64);
  const float rlog = __log2f(sum);

  f32x4 o[4];
  #pragma unroll
  for (int dt = 0; dt < 4; ++dt) o[dt] = (f32x4){0.f, 0.f, 0.f, 0.f};

  for (int t = 0; t < NT; ++t){
    __syncthreads();
    stage_rows_bf16(Kl, Kb + (size_t)t * 64 * DKC, tid);
    stage_vT_bf16 (Vt, Vb + (size_t)t * 64 * DKC, tid);
    __syncthreads();
    f32x4 acc[4];
    #pragma unroll
    for (int kt = 0; kt < 4; ++kt){
      const short8v kf0 = *(const short8v*)&Kl[swz(kt * 16 + ll, lh * 8)];
      const short8v kf1 = *(const short8v*)&Kl[swz(kt * 16 + ll, 32 + lh * 8)];
      f32x4 a = (f32x4){0.f, 0.f, 0.f, 0.f};
      a = __builtin_amdgcn_mfma_f32_16x16x32_bf16(kf0, qf[0], a, 0, 0, 0);
      a = __builtin_amdgcn_mfma_f32_16x16x32_bf16(kf1, qf[1], a, 0, 0, 0);
      acc[kt] = a;
    }
    unsigned long long wb = 0;
    if constexpr (BITS) wb = bitsg[(size_t)qrow * NT + t];
    #pragma unroll
    for (int kt = 0; kt < 4; ++kt){
      float p[4];
      #pragma unroll
      for (int j = 0; j < 4; ++j){
        const int bi = kt * 16 + lh * 4 + j;
        int keep;
        if constexpr (BITS) keep = (int)((wb >> bi) & 1ull);
        else                keep = maskg[(size_t)qrow * S_LEN + t * 64 + bi] != 0;
        p[j] = exp2f(keep ? fmaf(acc[kt][j], C_SC, -rlog) : NEGV);
      }
      f32x4 pv; pv[0]=p[0]; pv[1]=p[1]; pv[2]=p[2]; pv[3]=p[3];
      __builtin_nontemporal_store(pv, (f32x4*)&probsb[(size_t)qrow * S_LEN + t * 64 + kt * 16 + lh * 4]);
      short4 ps; ps.x=f2bf(p[0]); ps.y=f2bf(p[1]); ps.z=f2bf(p[2]); ps.w=f2bf(p[3]);
      *(short4*)&Pl[wid * 1024 + swz(ll, kt * 16 + lh * 4)] = ps;
    }
    asm volatile("s_waitcnt lgkmcnt(0)" ::: "memory");
    __builtin_amdgcn_sched_barrier(0);
    #pragma unroll
    for (int k32 = 0; k32 < 2; ++k32){
      const short8v pf = *(const short8v*)&Pl[wid * 1024 + swz(ll, k32 * 32 + lh * 8)];
      #pragma unroll
      for (int dt = 0; dt < 4; ++dt){
        const short8v vf = *(const short8v*)&Vt[swz(dt * 16 + ll, k32 * 32 + lh * 8)];
        o[dt] = __builtin_amdgcn_mfma_f32_16x16x32_bf16(pf, vf, o[dt], 0, 0, 0);
      }
    }
  }

  #pragma unroll
  for (int dt = 0; dt < 4; ++dt)
    #pragma unroll
    for (int j = 0; j < 4; ++j)
      __builtin_nontemporal_store(o[dt][j], &outb[(size_t)(qbase + wid * 16 + lh * 4 + j) * DKC + dt * 16 + ll]);
}

extern "C" void kernel_launch(void* const* d_in, const int* in_sizes, int n_in,
                              void* d_out, int out_size, void* d_ws, size_t ws_size,
                              hipStream_t stream) {
  const float* Q    = (const float*)d_in[0];
  const float* K    = (const float*)d_in[1];
  const float* V    = (const float*)d_in[2];
  const int*   mask = (const int*)d_in[3];

  float* out   = (float*)d_out;
  float* probs = out + (size_t)4 * 16 * 2048 * 64;

  const size_t bitsB = (size_t)S_LEN * S_LEN / 8;          // 512 KiB
  const size_t imgB  = (size_t)64 * NT * 4096 * 2;         // 16 MiB each
  unsigned long long* bits = (unsigned long long*)d_ws;
  short* Kimg = (short*)((char*)d_ws + bitsB);
  short* Vimg = (short*)((char*)d_ws + bitsB + imgB);
  short* Qimg = (short*)((char*)d_ws + bitsB + 2 * imgB);

  int mode;
  if      (ws_size >= bitsB + 3 * imgB) mode = 2;
  else if (ws_size >= bitsB)            mode = 1;
  else                                  mode = 0;

  if (mode == 2){
    kvq_convert<<<64 * NT, 256, 0, stream>>>(K, V, Q, mask, bits, Kimg, Vimg, Qimg);
    attn_f<<<64 * 32, 256, 0, stream>>>(Qimg, bits, Kimg, Vimg, out, probs);
  } else if (mode == 1){
    maskpack_kernel<<<256, 256, 0, stream>>>(mask, bits);
    attn_fb<1><<<64 * 32, 256, 0, stream>>>(Q, K, V, mask, bits, out, probs);
  } else {
    attn_fb<0><<<64 * 32, 256, 0, stream>>>(Q, K, V, mask, bits, out, probs);
  }
}

// Round 13
// 394.144 us; speedup vs baseline: 1.2019x; 1.0355x over previous
//
#include <hip/hip_runtime.h>
#include <hip/hip_bf16.h>

#define S_LEN 2048
#define NT    32
#define DKC   64
#define NEGV  (-1e9f)
// 0.125 * log2(e): folds the 1/sqrt(64) scale and the exp->exp2 conversion
#define C_SC  0.18033688011112042f

typedef __attribute__((ext_vector_type(8))) short short8v;
typedef __attribute__((ext_vector_type(4))) float f32x4;
typedef __attribute__((ext_vector_type(2))) unsigned uint2v;

__device__ __forceinline__ short f2bf(float f){
  unsigned u = __builtin_bit_cast(unsigned, f);
  u += 0x7fffu + ((u >> 16) & 1u);          // RNE to bf16 (images)
  return (short)(u >> 16);
}

// pack two floats -> bf16 pair (round-half-up; P in [0,1], error <= 2^-9 rel)
__device__ __forceinline__ unsigned packbf(float a, float b){
  const unsigned ua = __builtin_bit_cast(unsigned, a) + 0x8000u;
  const unsigned ub = __builtin_bit_cast(unsigned, b) + 0x8000u;
  return (ua >> 16) | (ub & 0xFFFF0000u);
}

// masked value: keep f where bit j of nib is set, else +0.0f (2 VALU: sbfe + and)
__device__ __forceinline__ float mask_and(float f, unsigned nib, int j){
  const int m = __builtin_amdgcn_sbfe(nib, j, 1);      // 0 or 0xFFFFFFFF
  return __builtin_bit_cast(float, m & __builtin_bit_cast(int, f));
}

// swizzled element index for a [rows][64] bf16 tile (128B rows): XOR bits 3-5
__device__ __forceinline__ int swz(int row, int col){
  return (row * 64 + col) ^ ((row & 7) << 3);
}

// chunked XCD decode: all 32 q-tiles (or k-tiles) of a bh on XCD bh&7
__device__ __forceinline__ void xcd_decode(int p, int& bh, int& qt){
  const int xcd = p & 7;
  const int n   = p >> 3;
  bh = ((n >> 5) << 3) | xcd;
  qt = n & 31;
}

// ---------------- fallback staging (no-ws path) ----------------
__device__ __forceinline__ void stage_rows_bf16(short* dst, const float* src, int tid){
  const int r  = tid >> 2;
  const int c0 = (tid & 3) * 16;
  const float* p = src + (size_t)r * DKC + c0;
  float4 a0 = *(const float4*)(p);
  float4 a1 = *(const float4*)(p + 4);
  float4 a2 = *(const float4*)(p + 8);
  float4 a3 = *(const float4*)(p + 12);
  short8v s0, s1;
  s0[0]=f2bf(a0.x); s0[1]=f2bf(a0.y); s0[2]=f2bf(a0.z); s0[3]=f2bf(a0.w);
  s0[4]=f2bf(a1.x); s0[5]=f2bf(a1.y); s0[6]=f2bf(a1.z); s0[7]=f2bf(a1.w);
  s1[0]=f2bf(a2.x); s1[1]=f2bf(a2.y); s1[2]=f2bf(a2.z); s1[3]=f2bf(a2.w);
  s1[4]=f2bf(a3.x); s1[5]=f2bf(a3.y); s1[6]=f2bf(a3.z); s1[7]=f2bf(a3.w);
  *(short8v*)&dst[swz(r, c0)]     = s0;
  *(short8v*)&dst[swz(r, c0 + 8)] = s1;
}

__device__ __forceinline__ void stage_vT_bf16(short* dst, const float* src, int tid){
  const int k  = tid >> 4;
  const int d0 = (tid & 15) * 4;
  #pragma unroll
  for (int i = 0; i < 4; ++i){
    const int kk = k + 16 * i;
    const float4 v = *(const float4*)(src + (size_t)kk * DKC + d0);
    dst[swz(d0 + 0, kk)] = f2bf(v.x);
    dst[swz(d0 + 1, kk)] = f2bf(v.y);
    dst[swz(d0 + 2, kk)] = f2bf(v.z);
    dst[swz(d0 + 3, kk)] = f2bf(v.w);
  }
}

// ---------------- standalone maskpack (mode 1 only) ----------------
__global__ void maskpack_kernel(const int* __restrict__ mask, unsigned long long* __restrict__ bits){
  const int w    = blockIdx.x * 4 + (threadIdx.x >> 6);
  const int lane = threadIdx.x & 63;
  for (int i = 0; i < 64; ++i){
    const size_t word = (size_t)w * 64 + i;
    const int v = mask[word * 64 + lane];
    const unsigned long long b = __ballot(v != 0);
    if (lane == 0) bits[word] = b;
  }
}

// Convert one 64x64 tile: K -> bf16 swizzled [r][d], V -> transposed swizzled [d][k],
// Q -> plain row-major bf16; plus pack 32 mask words per block (8 per wave).
__global__ __launch_bounds__(256) void kvq_convert(
    const float* __restrict__ Kg, const float* __restrict__ Vg, const float* __restrict__ Qg,
    const int* __restrict__ mask, unsigned long long* __restrict__ bits,
    short* __restrict__ Kimg, short* __restrict__ Vimg, short* __restrict__ Qimg){
  __shared__ float Vf[64][65];
  const int tid  = threadIdx.x;
  const int wid  = tid >> 6;
  const int lane = tid & 63;
  int bh, t;
  xcd_decode(blockIdx.x, bh, t);
  const size_t tile = (size_t)bh * NT + t;
  const float* Kb = Kg + tile * (64 * 64);
  const float* Vb = Vg + tile * (64 * 64);
  const float* Qb = Qg + tile * (64 * 64);
  short* Ki = Kimg + tile * 4096;
  short* Vi = Vimg + tile * 4096;
  short* Qi = Qimg + tile * 4096;

  // mask packing: wave gw handles words gw*8 .. gw*8+7
  {
    const int gw = blockIdx.x * 4 + wid;
    #pragma unroll
    for (int i = 0; i < 8; ++i){
      const size_t word = (size_t)gw * 8 + i;
      const int v = mask[word * 64 + lane];
      const unsigned long long b = __ballot(v != 0);
      if (lane == 0) bits[word] = b;
    }
  }

  // K (swizzled) + Q (plain): direct row conversion
  {
    const int r = tid >> 2, c0 = (tid & 3) * 16;
    const float* p = Kb + (size_t)r * 64 + c0;
    float4 a0 = *(const float4*)(p);
    float4 a1 = *(const float4*)(p + 4);
    float4 a2 = *(const float4*)(p + 8);
    float4 a3 = *(const float4*)(p + 12);
    short8v s0, s1;
    s0[0]=f2bf(a0.x); s0[1]=f2bf(a0.y); s0[2]=f2bf(a0.z); s0[3]=f2bf(a0.w);
    s0[4]=f2bf(a1.x); s0[5]=f2bf(a1.y); s0[6]=f2bf(a1.z); s0[7]=f2bf(a1.w);
    s1[0]=f2bf(a2.x); s1[1]=f2bf(a2.y); s1[2]=f2bf(a2.z); s1[3]=f2bf(a2.w);
    s1[4]=f2bf(a3.x); s1[5]=f2bf(a3.y); s1[6]=f2bf(a3.z); s1[7]=f2bf(a3.w);
    *(short8v*)&Ki[swz(r, c0)]     = s0;
    *(short8v*)&Ki[swz(r, c0 + 8)] = s1;

    const float* q = Qb + (size_t)r * 64 + c0;
    float4 b0 = *(const float4*)(q);
    float4 b1 = *(const float4*)(q + 4);
    float4 b2 = *(const float4*)(q + 8);
    float4 b3 = *(const float4*)(q + 12);
    short8v t0, t1;
    t0[0]=f2bf(b0.x); t0[1]=f2bf(b0.y); t0[2]=f2bf(b0.z); t0[3]=f2bf(b0.w);
    t0[4]=f2bf(b1.x); t0[5]=f2bf(b1.y); t0[6]=f2bf(b1.z); t0[7]=f2bf(b1.w);
    t1[0]=f2bf(b2.x); t1[1]=f2bf(b2.y); t1[2]=f2bf(b2.z); t1[3]=f2bf(b2.w);
    t1[4]=f2bf(b3.x); t1[5]=f2bf(b3.y); t1[6]=f2bf(b3.z); t1[7]=f2bf(b3.w);
    *(short8v*)&Qi[r * 64 + c0]     = t0;
    *(short8v*)&Qi[r * 64 + c0 + 8] = t1;
  }
  // V: LDS transpose
  {
    const int k = tid >> 2, c0 = (tid & 3) * 16;
    const float* p = Vb + (size_t)k * 64 + c0;
    float4 a0 = *(const float4*)(p);
    float4 a1 = *(const float4*)(p + 4);
    float4 a2 = *(const float4*)(p + 8);
    float4 a3 = *(const float4*)(p + 12);
    Vf[k][c0+0]=a0.x; Vf[k][c0+1]=a0.y; Vf[k][c0+2]=a0.z; Vf[k][c0+3]=a0.w;
    Vf[k][c0+4]=a1.x; Vf[k][c0+5]=a1.y; Vf[k][c0+6]=a1.z; Vf[k][c0+7]=a1.w;
    Vf[k][c0+8]=a2.x; Vf[k][c0+9]=a2.y; Vf[k][c0+10]=a2.z; Vf[k][c0+11]=a2.w;
    Vf[k][c0+12]=a3.x; Vf[k][c0+13]=a3.y; Vf[k][c0+14]=a3.z; Vf[k][c0+15]=a3.w;
  }
  __syncthreads();
  {
    const int d = tid >> 2, k0 = (tid & 3) * 16;
    short8v s0, s1;
    #pragma unroll
    for (int i = 0; i < 8; ++i) s0[i] = f2bf(Vf[k0 + i][d]);
    #pragma unroll
    for (int i = 0; i < 8; ++i) s1[i] = f2bf(Vf[k0 + 8 + i][d]);
    *(short8v*)&Vi[swz(d, k0)]     = s0;
    *(short8v*)&Vi[swz(d, k0 + 8)] = s1;
  }
}

// ---------------- FUSED: phase 1 row sums + phase 2 probs/PV ----------------
// P slab is bf16 [16 rows][136] per wave (2 tiles = 128 cols + 8 pad).
// PV reads bf16 directly (R11-proven path); flush expands bf16->fp32 (<<16, exact)
// and writes 512B-contiguous runs per row.
__global__ __launch_bounds__(256) void attn_f(
    const short* __restrict__ Qimg, const unsigned long long* __restrict__ bitsg,
    const short* __restrict__ Kimg, const short* __restrict__ Vimg,
    float* __restrict__ outg, float* __restrict__ probsg)
{
  __shared__ __align__(16) short Pb[4][16][136];   // per-wave bf16 P slab, 17.4KB total

  const int tid  = threadIdx.x;
  const int wid  = tid >> 6;
  const int lane = tid & 63;
  const int lh   = lane >> 4;
  const int ll   = lane & 15;

  int bh, qt;
  xcd_decode(blockIdx.x, bh, qt);
  const int qrow = qt * 64 + wid * 16 + ll;

  const short* Qib = Qimg + (size_t)bh * S_LEN * 64;
  const short* Kib = Kimg + (size_t)bh * NT * 4096;
  const short* Vib = Vimg + (size_t)bh * NT * 4096;
  float* outb = outg + (size_t)bh * S_LEN * DKC;
  const unsigned long long* wbp = bitsg + (size_t)qrow * NT;
  float* probsb = probsg + (size_t)bh * S_LEN * S_LEN;

  short8v qf[2];
  qf[0] = *(const short8v*)(Qib + (size_t)qrow * 64 + lh * 8);
  qf[1] = *(const short8v*)(Qib + (size_t)qrow * 64 + 32 + lh * 8);

  // ===== phase 1: row sums (lean register footprint) =====
  float s4[4] = {0.f, 0.f, 0.f, 0.f};
  {
    unsigned long long wb = wbp[0];
    #pragma unroll 2
    for (int t = 0; t < NT; ++t){
      const short* Kt_ = Kib + (size_t)t * 4096;
      const unsigned long long wb_next = (t + 1 < NT) ? wbp[t + 1] : 0;
      short8v kf[8];
      #pragma unroll
      for (int kt = 0; kt < 4; ++kt){
        kf[kt*2+0] = *(const short8v*)(Kt_ + swz(kt * 16 + ll, lh * 8));
        kf[kt*2+1] = *(const short8v*)(Kt_ + swz(kt * 16 + ll, 32 + lh * 8));
      }
      #pragma unroll
      for (int kt = 0; kt < 4; ++kt){
        f32x4 a = (f32x4){0.f, 0.f, 0.f, 0.f};
        a = __builtin_amdgcn_mfma_f32_16x16x32_bf16(kf[kt*2+0], qf[0], a, 0, 0, 0);
        a = __builtin_amdgcn_mfma_f32_16x16x32_bf16(kf[kt*2+1], qf[1], a, 0, 0, 0);
        const unsigned nib = (unsigned)(wb >> (kt * 16 + lh * 4));
        #pragma unroll
        for (int j = 0; j < 4; ++j)
          s4[j] += mask_and(exp2f(a[j] * C_SC), nib, j);
      }
      wb = wb_next;
    }
  }
  float sum = (s4[0] + s4[1]) + (s4[2] + s4[3]);
  sum += __shfl_xor(sum, 16, 64);
  sum += __shfl_xor(sum, 32, 64);
  const float rlog = __log2f(sum);     // stays in-register

  // ===== phase 2: probs + O = P.V =====
  f32x4 o[4];
  #pragma unroll
  for (int dt = 0; dt < 4; ++dt) o[dt] = (f32x4){0.f, 0.f, 0.f, 0.f};

  short* Pbw = &Pb[wid][0][0];
  const int lhi = lane >> 5;            // flush decomposition: 2 rows x 32 lanes
  const int llo = lane & 31;

  for (int t = 0; t < NT; ++t){
    const unsigned long long wb = wbp[t];
    const short* Kt_ = Kib + (size_t)t * 4096;
    const short* Vt_ = Vib + (size_t)t * 4096;
    const int pb = (t & 1) * 64;        // column base within the 128-col slab

    // ---- h=0 loads FIRST (flush stores below stay younger than them) ----
    short8v kf0[4], vf0[4];
    #pragma unroll
    for (int q = 0; q < 2; ++q){
      kf0[q*2+0] = *(const short8v*)(Kt_ + swz(q * 16 + ll, lh * 8));
      kf0[q*2+1] = *(const short8v*)(Kt_ + swz(q * 16 + ll, 32 + lh * 8));
    }
    #pragma unroll
    for (int dt = 0; dt < 4; ++dt)
      vf0[dt] = *(const short8v*)(Vt_ + swz(dt * 16 + ll, lh * 8));

    // ---- flush previous PAIR of tiles: 8 insts, 2 rows x 512B contiguous each ----
    if (t >= 2 && (t & 1) == 0){
      #pragma unroll
      for (int rr = 0; rr < 8; ++rr){
        const uint2v pk = *(const uint2v*)&Pbw[(rr * 2 + lhi) * 136 + llo * 4];
        f32x4 pv;
        pv[0] = __builtin_bit_cast(float, pk[0] << 16);
        pv[1] = __builtin_bit_cast(float, pk[0] & 0xFFFF0000u);
        pv[2] = __builtin_bit_cast(float, pk[1] << 16);
        pv[3] = __builtin_bit_cast(float, pk[1] & 0xFFFF0000u);
        __builtin_nontemporal_store(pv,
          (f32x4*)&probsb[(size_t)(qt * 64 + wid * 16 + rr * 2 + lhi) * S_LEN + (t - 2) * 64 + llo * 4]);
      }
    }

    // ---- h=0 compute ----
    {
      f32x4 acc[2];
      #pragma unroll
      for (int q = 0; q < 2; ++q){
        f32x4 a = (f32x4){0.f, 0.f, 0.f, 0.f};
        a = __builtin_amdgcn_mfma_f32_16x16x32_bf16(kf0[q*2+0], qf[0], a, 0, 0, 0);
        a = __builtin_amdgcn_mfma_f32_16x16x32_bf16(kf0[q*2+1], qf[1], a, 0, 0, 0);
        acc[q] = a;
      }
      #pragma unroll
      for (int q = 0; q < 2; ++q){
        const int kt = q;
        const unsigned nib = (unsigned)(wb >> (kt * 16 + lh * 4));
        float p[4];
        #pragma unroll
        for (int j = 0; j < 4; ++j)
          p[j] = mask_and(exp2f(fmaf(acc[q][j], C_SC, -rlog)), nib, j);
        uint2v pk; pk[0] = packbf(p[0], p[1]); pk[1] = packbf(p[2], p[3]);
        *(uint2v*)&Pbw[ll * 136 + pb + kt * 16 + lh * 4] = pk;
      }
      const short8v pf = *(const short8v*)&Pbw[ll * 136 + pb + lh * 8];
      #pragma unroll
      for (int dt = 0; dt < 4; ++dt)
        o[dt] = __builtin_amdgcn_mfma_f32_16x16x32_bf16(pf, vf0[dt], o[dt], 0, 0, 0);
    }

    // ---- h=1 ----
    {
      short8v kf1[4], vf1[4];
      #pragma unroll
      for (int q = 0; q < 2; ++q){
        const int kt = 2 + q;
        kf1[q*2+0] = *(const short8v*)(Kt_ + swz(kt * 16 + ll, lh * 8));
        kf1[q*2+1] = *(const short8v*)(Kt_ + swz(kt * 16 + ll, 32 + lh * 8));
      }
      #pragma unroll
      for (int dt = 0; dt < 4; ++dt)
        vf1[dt] = *(const short8v*)(Vt_ + swz(dt * 16 + ll, 32 + lh * 8));

      f32x4 acc[2];
      #pragma unroll
      for (int q = 0; q < 2; ++q){
        f32x4 a = (f32x4){0.f, 0.f, 0.f, 0.f};
        a = __builtin_amdgcn_mfma_f32_16x16x32_bf16(kf1[q*2+0], qf[0], a, 0, 0, 0);
        a = __builtin_amdgcn_mfma_f32_16x16x32_bf16(kf1[q*2+1], qf[1], a, 0, 0, 0);
        acc[q] = a;
      }
      #pragma unroll
      for (int q = 0; q < 2; ++q){
        const int kt = 2 + q;
        const unsigned nib = (unsigned)(wb >> (kt * 16 + lh * 4));
        float p[4];
        #pragma unroll
        for (int j = 0; j < 4; ++j)
          p[j] = mask_and(exp2f(fmaf(acc[q][j], C_SC, -rlog)), nib, j);
        uint2v pk; pk[0] = packbf(p[0], p[1]); pk[1] = packbf(p[2], p[3]);
        *(uint2v*)&Pbw[ll * 136 + pb + kt * 16 + lh * 4] = pk;
      }
      const short8v pf = *(const short8v*)&Pbw[ll * 136 + pb + 32 + lh * 8];
      #pragma unroll
      for (int dt = 0; dt < 4; ++dt)
        o[dt] = __builtin_amdgcn_mfma_f32_16x16x32_bf16(pf, vf1[dt], o[dt], 0, 0, 0);
    }
  }

  // final flush (tiles NT-2, NT-1)
  #pragma unroll
  for (int rr = 0; rr < 8; ++rr){
    const uint2v pk = *(const uint2v*)&Pbw[(rr * 2 + lhi) * 136 + llo * 4];
    f32x4 pv;
    pv[0] = __builtin_bit_cast(float, pk[0] << 16);
    pv[1] = __builtin_bit_cast(float, pk[0] & 0xFFFF0000u);
    pv[2] = __builtin_bit_cast(float, pk[1] << 16);
    pv[3] = __builtin_bit_cast(float, pk[1] & 0xFFFF0000u);
    __builtin_nontemporal_store(pv,
      (f32x4*)&probsb[(size_t)(qt * 64 + wid * 16 + rr * 2 + lhi) * S_LEN + (NT - 2) * 64 + llo * 4]);
  }

  #pragma unroll
  for (int dt = 0; dt < 4; ++dt)
    #pragma unroll
    for (int j = 0; j < 4; ++j)
      __builtin_nontemporal_store(o[dt][j], &outb[(size_t)(qt * 64 + wid * 16 + lh * 4 + j) * DKC + dt * 16 + ll]);
}

// ---------------- fallback: monolithic two-pass with LDS staging ----------------
template<int BITS>
__global__ __launch_bounds__(256) void attn_fb(
    const float* __restrict__ Qg, const float* __restrict__ Kg, const float* __restrict__ Vg,
    const int* __restrict__ maskg, const unsigned long long* __restrict__ bitsg,
    float* __restrict__ outg, float* __restrict__ probsg)
{
  __shared__ __align__(16) short Kl[4096];
  __shared__ __align__(16) short Vt[4096];
  __shared__ __align__(16) short Pl[4096];

  const int tid  = threadIdx.x;
  const int wid  = tid >> 6;
  const int lane = tid & 63;
  const int lh   = lane >> 4;
  const int ll   = lane & 15;

  const int qt    = blockIdx.x & 31;
  const int bh    = blockIdx.x >> 5;
  const int qbase = qt * 64;
  const int qrow  = qbase + wid * 16 + ll;

  const float* Qb = Qg + (size_t)bh * S_LEN * DKC;
  const float* Kb = Kg + (size_t)bh * S_LEN * DKC;
  const float* Vb = Vg + (size_t)bh * S_LEN * DKC;
  float* outb   = outg   + (size_t)bh * S_LEN * DKC;
  float* probsb = probsg + (size_t)bh * S_LEN * S_LEN;

  short8v qf[2];
  #pragma unroll
  for (int h = 0; h < 2; ++h){
    const float4 a = *(const float4*)(Qb + (size_t)qrow * DKC + h * 32 + lh * 8);
    const float4 b = *(const float4*)(Qb + (size_t)qrow * DKC + h * 32 + lh * 8 + 4);
    short8v t;
    t[0]=f2bf(a.x); t[1]=f2bf(a.y); t[2]=f2bf(a.z); t[3]=f2bf(a.w);
    t[4]=f2bf(b.x); t[5]=f2bf(b.y); t[6]=f2bf(b.z); t[7]=f2bf(b.w);
    qf[h] = t;
  }

  float sum = 0.f;
  for (int t = 0; t < NT; ++t){
    __syncthreads();
    stage_rows_bf16(Kl, Kb + (size_t)t * 64 * DKC, tid);
    __syncthreads();
    unsigned long long wb = 0;
    if constexpr (BITS) wb = bitsg[(size_t)qrow * NT + t];
    #pragma unroll
    for (int kt = 0; kt < 4; ++kt){
      const short8v kf0 = *(const short8v*)&Kl[swz(kt * 16 + ll, lh * 8)];
      const short8v kf1 = *(const short8v*)&Kl[swz(kt * 16 + ll, 32 + lh * 8)];
      f32x4 a = (f32x4){0.f, 0.f, 0.f, 0.f};
      a = __builtin_amdgcn_mfma_f32_16x16x32_bf16(kf0, qf[0], a, 0, 0, 0);
      a = __builtin_amdgcn_mfma_f32_16x16x32_bf16(kf1, qf[1], a, 0, 0, 0);
      #pragma unroll
      for (int j = 0; j < 4; ++j){
        const int bi = kt * 16 + lh * 4 + j;
        int keep;
        if constexpr (BITS) keep = (int)((wb >> bi) & 1ull);
        else                keep = maskg[(size_t)qrow * S_LEN + t * 64 + bi] != 0;
        sum += exp2f(keep ? a[j] * C_SC : NEGV);
      }
    }
  }
  sum += __shfl_xor(sum, 16, 64);
  sum += __shfl_xor(sum, 32, 64);
  const float rlog = __log2f(sum);

  f32x4 o[4];
  #pragma unroll
  for (int dt = 0; dt < 4; ++dt) o[dt] = (f32x4){0.f, 0.f, 0.f, 0.f};

  for (int t = 0; t < NT; ++t){
    __syncthreads();
    stage_rows_bf16(Kl, Kb + (size_t)t * 64 * DKC, tid);
    stage_vT_bf16 (Vt, Vb + (size_t)t * 64 * DKC, tid);
    __syncthreads();
    f32x4 acc[4];
    #pragma unroll
    for (int kt = 0; kt < 4; ++kt){
      const short8v kf0 = *(const short8v*)&Kl[swz(kt * 16 + ll, lh * 8)];
      const short8v kf1 = *(const short8v*)&Kl[swz(kt * 16 + ll, 32 + lh * 8)];
      f32x4 a = (f32x4){0.f, 0.f, 0.f, 0.f};
      a = __builtin_amdgcn_mfma_f32_16x16x32_bf16(kf0, qf[0], a, 0, 0, 0);
      a = __builtin_amdgcn_mfma_f32_16x16x32_bf16(kf1, qf[1], a, 0, 0, 0);
      acc[kt] = a;
    }
    unsigned long long wb = 0;
    if constexpr (BITS) wb = bitsg[(size_t)qrow * NT + t];
    #pragma unroll
    for (int kt = 0; kt < 4; ++kt){
      float p[4];
      #pragma unroll
      for (int j = 0; j < 4; ++j){
        const int bi = kt * 16 + lh * 4 + j;
        int keep;
        if constexpr (BITS) keep = (int)((wb >> bi) & 1ull);
        else                keep = maskg[(size_t)qrow * S_LEN + t * 64 + bi] != 0;
        p[j] = exp2f(keep ? fmaf(acc[kt][j], C_SC, -rlog) : NEGV);
      }
      f32x4 pv; pv[0]=p[0]; pv[1]=p[1]; pv[2]=p[2]; pv[3]=p[3];
      __builtin_nontemporal_store(pv, (f32x4*)&probsb[(size_t)qrow * S_LEN + t * 64 + kt * 16 + lh * 4]);
      short4 ps; ps.x=f2bf(p[0]); ps.y=f2bf(p[1]); ps.z=f2bf(p[2]); ps.w=f2bf(p[3]);
      *(short4*)&Pl[wid * 1024 + swz(ll, kt * 16 + lh * 4)] = ps;
    }
    asm volatile("s_waitcnt lgkmcnt(0)" ::: "memory");
    __builtin_amdgcn_sched_barrier(0);
    #pragma unroll
    for (int k32 = 0; k32 < 2; ++k32){
      const short8v pf = *(const short8v*)&Pl[wid * 1024 + swz(ll, k32 * 32 + lh * 8)];
      #pragma unroll
      for (int dt = 0; dt < 4; ++dt){
        const short8v vf = *(const short8v*)&Vt[swz(dt * 16 + ll, k32 * 32 + lh * 8)];
        o[dt] = __builtin_amdgcn_mfma_f32_16x16x32_bf16(pf, vf, o[dt], 0, 0, 0);
      }
    }
  }

  #pragma unroll
  for (int dt = 0; dt < 4; ++dt)
    #pragma unroll
    for (int j = 0; j < 4; ++j)
      __builtin_nontemporal_store(o[dt][j], &outb[(size_t)(qbase + wid * 16 + lh * 4 + j) * DKC + dt * 16 + ll]);
}

extern "C" void kernel_launch(void* const* d_in, const int* in_sizes, int n_in,
                              void* d_out, int out_size, void* d_ws, size_t ws_size,
                              hipStream_t stream) {
  const float* Q    = (const float*)d_in[0];
  const float* K    = (const float*)d_in[1];
  const float* V    = (const float*)d_in[2];
  const int*   mask = (const int*)d_in[3];

  float* out   = (float*)d_out;
  float* probs = out + (size_t)4 * 16 * 2048 * 64;

  const size_t bitsB = (size_t)S_LEN * S_LEN / 8;          // 512 KiB
  const size_t imgB  = (size_t)64 * NT * 4096 * 2;         // 16 MiB each
  unsigned long long* bits = (unsigned long long*)d_ws;
  short* Kimg = (short*)((char*)d_ws + bitsB);
  short* Vimg = (short*)((char*)d_ws + bitsB + imgB);
  short* Qimg = (short*)((char*)d_ws + bitsB + 2 * imgB);

  int mode;
  if      (ws_size >= bitsB + 3 * imgB) mode = 2;
  else if (ws_size >= bitsB)            mode = 1;
  else                                  mode = 0;

  if (mode == 2){
    kvq_convert<<<64 * NT, 256, 0, stream>>>(K, V, Q, mask, bits, Kimg, Vimg, Qimg);
    attn_f<<<64 * 32, 256, 0, stream>>>(Qimg, bits, Kimg, Vimg, out, probs);
  } else if (mode == 1){
    maskpack_kernel<<<256, 256, 0, stream>>>(mask, bits);
    attn_fb<1><<<64 * 32, 256, 0, stream>>>(Q, K, V, mask, bits, out, probs);
  } else {
    attn_fb<0><<<64 * 32, 256, 0, stream>>>(Q, K, V, mask, bits, out, probs);
  }
}

// Round 14
// 392.587 us; speedup vs baseline: 1.2067x; 1.0040x over previous
//
#include <hip/hip_runtime.h>
#include <hip/hip_bf16.h>

#define S_LEN 2048
#define NT    32
#define DKC   64
#define NEGV  (-1e9f)
// 0.125 * log2(e): folds the 1/sqrt(64) scale and the exp->exp2 conversion
#define C_SC  0.18033688011112042f

typedef __attribute__((ext_vector_type(8))) short short8v;
typedef __attribute__((ext_vector_type(4))) float f32x4;
typedef __attribute__((ext_vector_type(2))) unsigned uint2v;

__device__ __forceinline__ short f2bf(float f){
  unsigned u = __builtin_bit_cast(unsigned, f);
  u += 0x7fffu + ((u >> 16) & 1u);          // RNE to bf16 (images)
  return (short)(u >> 16);
}

// pack two floats -> bf16 pair (round-half-up; P in [0,1], error <= 2^-9 rel)
__device__ __forceinline__ unsigned packbf(float a, float b){
  const unsigned ua = __builtin_bit_cast(unsigned, a) + 0x8000u;
  const unsigned ub = __builtin_bit_cast(unsigned, b) + 0x8000u;
  return (ua >> 16) | (ub & 0xFFFF0000u);
}

// masked value: keep f where bit j of nib is set, else +0.0f (2 VALU: sbfe + and)
__device__ __forceinline__ float mask_and(float f, unsigned nib, int j){
  const int m = __builtin_amdgcn_sbfe(nib, j, 1);      // 0 or 0xFFFFFFFF
  return __builtin_bit_cast(float, m & __builtin_bit_cast(int, f));
}

// swizzled element index for a [rows][64] bf16 tile (128B rows): XOR bits 3-5
__device__ __forceinline__ int swz(int row, int col){
  return (row * 64 + col) ^ ((row & 7) << 3);
}

// chunked XCD decode: all 32 q-tiles (or k-tiles) of a bh on XCD bh&7
__device__ __forceinline__ void xcd_decode(int p, int& bh, int& qt){
  const int xcd = p & 7;
  const int n   = p >> 3;
  bh = ((n >> 5) << 3) | xcd;
  qt = n & 31;
}

// ---------------- fallback staging (no-ws path) ----------------
__device__ __forceinline__ void stage_rows_bf16(short* dst, const float* src, int tid){
  const int r  = tid >> 2;
  const int c0 = (tid & 3) * 16;
  const float* p = src + (size_t)r * DKC + c0;
  float4 a0 = *(const float4*)(p);
  float4 a1 = *(const float4*)(p + 4);
  float4 a2 = *(const float4*)(p + 8);
  float4 a3 = *(const float4*)(p + 12);
  short8v s0, s1;
  s0[0]=f2bf(a0.x); s0[1]=f2bf(a0.y); s0[2]=f2bf(a0.z); s0[3]=f2bf(a0.w);
  s0[4]=f2bf(a1.x); s0[5]=f2bf(a1.y); s0[6]=f2bf(a1.z); s0[7]=f2bf(a1.w);
  s1[0]=f2bf(a2.x); s1[1]=f2bf(a2.y); s1[2]=f2bf(a2.z); s1[3]=f2bf(a2.w);
  s1[4]=f2bf(a3.x); s1[5]=f2bf(a3.y); s1[6]=f2bf(a3.z); s1[7]=f2bf(a3.w);
  *(short8v*)&dst[swz(r, c0)]     = s0;
  *(short8v*)&dst[swz(r, c0 + 8)] = s1;
}

__device__ __forceinline__ void stage_vT_bf16(short* dst, const float* src, int tid){
  const int k  = tid >> 4;
  const int d0 = (tid & 15) * 4;
  #pragma unroll
  for (int i = 0; i < 4; ++i){
    const int kk = k + 16 * i;
    const float4 v = *(const float4*)(src + (size_t)kk * DKC + d0);
    dst[swz(d0 + 0, kk)] = f2bf(v.x);
    dst[swz(d0 + 1, kk)] = f2bf(v.y);
    dst[swz(d0 + 2, kk)] = f2bf(v.z);
    dst[swz(d0 + 3, kk)] = f2bf(v.w);
  }
}

// ---------------- standalone maskpack (mode 1 only) ----------------
__global__ void maskpack_kernel(const int* __restrict__ mask, unsigned long long* __restrict__ bits){
  const int w    = blockIdx.x * 4 + (threadIdx.x >> 6);
  const int lane = threadIdx.x & 63;
  for (int i = 0; i < 64; ++i){
    const size_t word = (size_t)w * 64 + i;
    const int v = mask[word * 64 + lane];
    const unsigned long long b = __ballot(v != 0);
    if (lane == 0) bits[word] = b;
  }
}

// Convert one 64x64 tile: K -> bf16 swizzled [r][d], V -> transposed swizzled [d][k],
// Q -> plain row-major bf16; plus pack 32 mask words per block (8 per wave).
__global__ __launch_bounds__(256) void kvq_convert(
    const float* __restrict__ Kg, const float* __restrict__ Vg, const float* __restrict__ Qg,
    const int* __restrict__ mask, unsigned long long* __restrict__ bits,
    short* __restrict__ Kimg, short* __restrict__ Vimg, short* __restrict__ Qimg){
  __shared__ float Vf[64][65];
  const int tid  = threadIdx.x;
  const int wid  = tid >> 6;
  const int lane = tid & 63;
  int bh, t;
  xcd_decode(blockIdx.x, bh, t);
  const size_t tile = (size_t)bh * NT + t;
  const float* Kb = Kg + tile * (64 * 64);
  const float* Vb = Vg + tile * (64 * 64);
  const float* Qb = Qg + tile * (64 * 64);
  short* Ki = Kimg + tile * 4096;
  short* Vi = Vimg + tile * 4096;
  short* Qi = Qimg + tile * 4096;

  // mask packing: wave gw handles words gw*8 .. gw*8+7
  {
    const int gw = blockIdx.x * 4 + wid;
    #pragma unroll
    for (int i = 0; i < 8; ++i){
      const size_t word = (size_t)gw * 8 + i;
      const int v = mask[word * 64 + lane];
      const unsigned long long b = __ballot(v != 0);
      if (lane == 0) bits[word] = b;
    }
  }

  // K (swizzled) + Q (plain): direct row conversion
  {
    const int r = tid >> 2, c0 = (tid & 3) * 16;
    const float* p = Kb + (size_t)r * 64 + c0;
    float4 a0 = *(const float4*)(p);
    float4 a1 = *(const float4*)(p + 4);
    float4 a2 = *(const float4*)(p + 8);
    float4 a3 = *(const float4*)(p + 12);
    short8v s0, s1;
    s0[0]=f2bf(a0.x); s0[1]=f2bf(a0.y); s0[2]=f2bf(a0.z); s0[3]=f2bf(a0.w);
    s0[4]=f2bf(a1.x); s0[5]=f2bf(a1.y); s0[6]=f2bf(a1.z); s0[7]=f2bf(a1.w);
    s1[0]=f2bf(a2.x); s1[1]=f2bf(a2.y); s1[2]=f2bf(a2.z); s1[3]=f2bf(a2.w);
    s1[4]=f2bf(a3.x); s1[5]=f2bf(a3.y); s1[6]=f2bf(a3.z); s1[7]=f2bf(a3.w);
    *(short8v*)&Ki[swz(r, c0)]     = s0;
    *(short8v*)&Ki[swz(r, c0 + 8)] = s1;

    const float* q = Qb + (size_t)r * 64 + c0;
    float4 b0 = *(const float4*)(q);
    float4 b1 = *(const float4*)(q + 4);
    float4 b2 = *(const float4*)(q + 8);
    float4 b3 = *(const float4*)(q + 12);
    short8v t0, t1;
    t0[0]=f2bf(b0.x); t0[1]=f2bf(b0.y); t0[2]=f2bf(b0.z); t0[3]=f2bf(b0.w);
    t0[4]=f2bf(b1.x); t0[5]=f2bf(b1.y); t0[6]=f2bf(b1.z); t0[7]=f2bf(b1.w);
    t1[0]=f2bf(b2.x); t1[1]=f2bf(b2.y); t1[2]=f2bf(b2.z); t1[3]=f2bf(b2.w);
    t1[4]=f2bf(b3.x); t1[5]=f2bf(b3.y); t1[6]=f2bf(b3.z); t1[7]=f2bf(b3.w);
    *(short8v*)&Qi[r * 64 + c0]     = t0;
    *(short8v*)&Qi[r * 64 + c0 + 8] = t1;
  }
  // V: LDS transpose
  {
    const int k = tid >> 2, c0 = (tid & 3) * 16;
    const float* p = Vb + (size_t)k * 64 + c0;
    float4 a0 = *(const float4*)(p);
    float4 a1 = *(const float4*)(p + 4);
    float4 a2 = *(const float4*)(p + 8);
    float4 a3 = *(const float4*)(p + 12);
    Vf[k][c0+0]=a0.x; Vf[k][c0+1]=a0.y; Vf[k][c0+2]=a0.z; Vf[k][c0+3]=a0.w;
    Vf[k][c0+4]=a1.x; Vf[k][c0+5]=a1.y; Vf[k][c0+6]=a1.z; Vf[k][c0+7]=a1.w;
    Vf[k][c0+8]=a2.x; Vf[k][c0+9]=a2.y; Vf[k][c0+10]=a2.z; Vf[k][c0+11]=a2.w;
    Vf[k][c0+12]=a3.x; Vf[k][c0+13]=a3.y; Vf[k][c0+14]=a3.z; Vf[k][c0+15]=a3.w;
  }
  __syncthreads();
  {
    const int d = tid >> 2, k0 = (tid & 3) * 16;
    short8v s0, s1;
    #pragma unroll
    for (int i = 0; i < 8; ++i) s0[i] = f2bf(Vf[k0 + i][d]);
    #pragma unroll
    for (int i = 0; i < 8; ++i) s1[i] = f2bf(Vf[k0 + 8 + i][d]);
    *(short8v*)&Vi[swz(d, k0)]     = s0;
    *(short8v*)&Vi[swz(d, k0 + 8)] = s1;
  }
}

// ---------------- FUSED: phase 1 row sums + phase 2 probs/PV ----------------
// P slab is bf16 [16 rows][264] per wave (4 tiles = 256 cols + 8 pad).
// PV reads bf16 directly; flush expands bf16->fp32 (<<16, exact) and writes
// one full row chunk per instruction: 64 lanes x 16B = 1024B contiguous.
__global__ __launch_bounds__(256) void attn_f(
    const short* __restrict__ Qimg, const unsigned long long* __restrict__ bitsg,
    const short* __restrict__ Kimg, const short* __restrict__ Vimg,
    float* __restrict__ outg, float* __restrict__ probsg)
{
  __shared__ __align__(16) short Pb[4][16][264];   // per-wave bf16 P slab, 33KB total

  const int tid  = threadIdx.x;
  const int wid  = tid >> 6;
  const int lane = tid & 63;
  const int lh   = lane >> 4;
  const int ll   = lane & 15;

  int bh, qt;
  xcd_decode(blockIdx.x, bh, qt);
  const int qrow = qt * 64 + wid * 16 + ll;

  const short* Qib = Qimg + (size_t)bh * S_LEN * 64;
  const short* Kib = Kimg + (size_t)bh * NT * 4096;
  const short* Vib = Vimg + (size_t)bh * NT * 4096;
  float* outb = outg + (size_t)bh * S_LEN * DKC;
  const unsigned long long* wbp = bitsg + (size_t)qrow * NT;
  float* probsb = probsg + (size_t)bh * S_LEN * S_LEN;

  short8v qf[2];
  qf[0] = *(const short8v*)(Qib + (size_t)qrow * 64 + lh * 8);
  qf[1] = *(const short8v*)(Qib + (size_t)qrow * 64 + 32 + lh * 8);

  // ===== phase 1: row sums (lean register footprint) =====
  float s4[4] = {0.f, 0.f, 0.f, 0.f};
  {
    unsigned long long wb = wbp[0];
    #pragma unroll 2
    for (int t = 0; t < NT; ++t){
      const short* Kt_ = Kib + (size_t)t * 4096;
      const unsigned long long wb_next = (t + 1 < NT) ? wbp[t + 1] : 0;
      short8v kf[8];
      #pragma unroll
      for (int kt = 0; kt < 4; ++kt){
        kf[kt*2+0] = *(const short8v*)(Kt_ + swz(kt * 16 + ll, lh * 8));
        kf[kt*2+1] = *(const short8v*)(Kt_ + swz(kt * 16 + ll, 32 + lh * 8));
      }
      #pragma unroll
      for (int kt = 0; kt < 4; ++kt){
        f32x4 a = (f32x4){0.f, 0.f, 0.f, 0.f};
        a = __builtin_amdgcn_mfma_f32_16x16x32_bf16(kf[kt*2+0], qf[0], a, 0, 0, 0);
        a = __builtin_amdgcn_mfma_f32_16x16x32_bf16(kf[kt*2+1], qf[1], a, 0, 0, 0);
        const unsigned nib = (unsigned)(wb >> (kt * 16 + lh * 4));
        #pragma unroll
        for (int j = 0; j < 4; ++j)
          s4[j] += mask_and(exp2f(a[j] * C_SC), nib, j);
      }
      wb = wb_next;
    }
  }
  float sum = (s4[0] + s4[1]) + (s4[2] + s4[3]);
  sum += __shfl_xor(sum, 16, 64);
  sum += __shfl_xor(sum, 32, 64);
  const float rlog = __log2f(sum);     // stays in-register

  // ===== phase 2: probs + O = P.V =====
  f32x4 o[4];
  #pragma unroll
  for (int dt = 0; dt < 4; ++dt) o[dt] = (f32x4){0.f, 0.f, 0.f, 0.f};

  short* Pbw = &Pb[wid][0][0];

  for (int t = 0; t < NT; ++t){
    const unsigned long long wb = wbp[t];
    const short* Kt_ = Kib + (size_t)t * 4096;
    const short* Vt_ = Vib + (size_t)t * 4096;
    const int pb = (t & 3) * 64;        // column base within the 256-col slab

    // ---- h=0 loads FIRST (flush stores below stay younger than them) ----
    short8v kf0[4], vf0[4];
    #pragma unroll
    for (int q = 0; q < 2; ++q){
      kf0[q*2+0] = *(const short8v*)(Kt_ + swz(q * 16 + ll, lh * 8));
      kf0[q*2+1] = *(const short8v*)(Kt_ + swz(q * 16 + ll, 32 + lh * 8));
    }
    #pragma unroll
    for (int dt = 0; dt < 4; ++dt)
      vf0[dt] = *(const short8v*)(Vt_ + swz(dt * 16 + ll, lh * 8));

    // ---- flush previous QUAD of tiles: 16 insts, each one row x 1024B contiguous ----
    if (t >= 4 && (t & 3) == 0){
      #pragma unroll
      for (int rr = 0; rr < 16; ++rr){
        const uint2v pk = *(const uint2v*)&Pbw[rr * 264 + lane * 4];
        f32x4 pv;
        pv[0] = __builtin_bit_cast(float, pk[0] << 16);
        pv[1] = __builtin_bit_cast(float, pk[0] & 0xFFFF0000u);
        pv[2] = __builtin_bit_cast(float, pk[1] << 16);
        pv[3] = __builtin_bit_cast(float, pk[1] & 0xFFFF0000u);
        __builtin_nontemporal_store(pv,
          (f32x4*)&probsb[(size_t)(qt * 64 + wid * 16 + rr) * S_LEN + (t - 4) * 64 + lane * 4]);
      }
    }

    // ---- h=0 compute ----
    {
      f32x4 acc[2];
      #pragma unroll
      for (int q = 0; q < 2; ++q){
        f32x4 a = (f32x4){0.f, 0.f, 0.f, 0.f};
        a = __builtin_amdgcn_mfma_f32_16x16x32_bf16(kf0[q*2+0], qf[0], a, 0, 0, 0);
        a = __builtin_amdgcn_mfma_f32_16x16x32_bf16(kf0[q*2+1], qf[1], a, 0, 0, 0);
        acc[q] = a;
      }
      #pragma unroll
      for (int q = 0; q < 2; ++q){
        const int kt = q;
        const unsigned nib = (unsigned)(wb >> (kt * 16 + lh * 4));
        float p[4];
        #pragma unroll
        for (int j = 0; j < 4; ++j)
          p[j] = mask_and(exp2f(fmaf(acc[q][j], C_SC, -rlog)), nib, j);
        uint2v pk; pk[0] = packbf(p[0], p[1]); pk[1] = packbf(p[2], p[3]);
        *(uint2v*)&Pbw[ll * 264 + pb + kt * 16 + lh * 4] = pk;
      }
      const short8v pf = *(const short8v*)&Pbw[ll * 264 + pb + lh * 8];
      #pragma unroll
      for (int dt = 0; dt < 4; ++dt)
        o[dt] = __builtin_amdgcn_mfma_f32_16x16x32_bf16(pf, vf0[dt], o[dt], 0, 0, 0);
    }

    // ---- h=1 ----
    {
      short8v kf1[4], vf1[4];
      #pragma unroll
      for (int q = 0; q < 2; ++q){
        const int kt = 2 + q;
        kf1[q*2+0] = *(const short8v*)(Kt_ + swz(kt * 16 + ll, lh * 8));
        kf1[q*2+1] = *(const short8v*)(Kt_ + swz(kt * 16 + ll, 32 + lh * 8));
      }
      #pragma unroll
      for (int dt = 0; dt < 4; ++dt)
        vf1[dt] = *(const short8v*)(Vt_ + swz(dt * 16 + ll, 32 + lh * 8));

      f32x4 acc[2];
      #pragma unroll
      for (int q = 0; q < 2; ++q){
        f32x4 a = (f32x4){0.f, 0.f, 0.f, 0.f};
        a = __builtin_amdgcn_mfma_f32_16x16x32_bf16(kf1[q*2+0], qf[0], a, 0, 0, 0);
        a = __builtin_amdgcn_mfma_f32_16x16x32_bf16(kf1[q*2+1], qf[1], a, 0, 0, 0);
        acc[q] = a;
      }
      #pragma unroll
      for (int q = 0; q < 2; ++q){
        const int kt = 2 + q;
        const unsigned nib = (unsigned)(wb >> (kt * 16 + lh * 4));
        float p[4];
        #pragma unroll
        for (int j = 0; j < 4; ++j)
          p[j] = mask_and(exp2f(fmaf(acc[q][j], C_SC, -rlog)), nib, j);
        uint2v pk; pk[0] = packbf(p[0], p[1]); pk[1] = packbf(p[2], p[3]);
        *(uint2v*)&Pbw[ll * 264 + pb + kt * 16 + lh * 4] = pk;
      }
      const short8v pf = *(const short8v*)&Pbw[ll * 264 + pb + 32 + lh * 8];
      #pragma unroll
      for (int dt = 0; dt < 4; ++dt)
        o[dt] = __builtin_amdgcn_mfma_f32_16x16x32_bf16(pf, vf1[dt], o[dt], 0, 0, 0);
    }
  }

  // final flush (tiles NT-4..NT-1)
  #pragma unroll
  for (int rr = 0; rr < 16; ++rr){
    const uint2v pk = *(const uint2v*)&Pbw[rr * 264 + lane * 4];
    f32x4 pv;
    pv[0] = __builtin_bit_cast(float, pk[0] << 16);
    pv[1] = __builtin_bit_cast(float, pk[0] & 0xFFFF0000u);
    pv[2] = __builtin_bit_cast(float, pk[1] << 16);
    pv[3] = __builtin_bit_cast(float, pk[1] & 0xFFFF0000u);
    __builtin_nontemporal_store(pv,
      (f32x4*)&probsb[(size_t)(qt * 64 + wid * 16 + rr) * S_LEN + (NT - 4) * 64 + lane * 4]);
  }

  #pragma unroll
  for (int dt = 0; dt < 4; ++dt)
    #pragma unroll
    for (int j = 0; j < 4; ++j)
      __builtin_nontemporal_store(o[dt][j], &outb[(size_t)(qt * 64 + wid * 16 + lh * 4 + j) * DKC + dt * 16 + ll]);
}

// ---------------- fallback: monolithic two-pass with LDS staging ----------------
template<int BITS>
__global__ __launch_bounds__(256) void attn_fb(
    const float* __restrict__ Qg, const float* __restrict__ Kg, const float* __restrict__ Vg,
    const int* __restrict__ maskg, const unsigned long long* __restrict__ bitsg,
    float* __restrict__ outg, float* __restrict__ probsg)
{
  __shared__ __align__(16) short Kl[4096];
  __shared__ __align__(16) short Vt[4096];
  __shared__ __align__(16) short Pl[4096];

  const int tid  = threadIdx.x;
  const int wid  = tid >> 6;
  const int lane = tid & 63;
  const int lh   = lane >> 4;
  const int ll   = lane & 15;

  const int qt    = blockIdx.x & 31;
  const int bh    = blockIdx.x >> 5;
  const int qbase = qt * 64;
  const int qrow  = qbase + wid * 16 + ll;

  const float* Qb = Qg + (size_t)bh * S_LEN * DKC;
  const float* Kb = Kg + (size_t)bh * S_LEN * DKC;
  const float* Vb = Vg + (size_t)bh * S_LEN * DKC;
  float* outb   = outg   + (size_t)bh * S_LEN * DKC;
  float* probsb = probsg + (size_t)bh * S_LEN * S_LEN;

  short8v qf[2];
  #pragma unroll
  for (int h = 0; h < 2; ++h){
    const float4 a = *(const float4*)(Qb + (size_t)qrow * DKC + h * 32 + lh * 8);
    const float4 b = *(const float4*)(Qb + (size_t)qrow * DKC + h * 32 + lh * 8 + 4);
    short8v t;
    t[0]=f2bf(a.x); t[1]=f2bf(a.y); t[2]=f2bf(a.z); t[3]=f2bf(a.w);
    t[4]=f2bf(b.x); t[5]=f2bf(b.y); t[6]=f2bf(b.z); t[7]=f2bf(b.w);
    qf[h] = t;
  }

  float sum = 0.f;
  for (int t = 0; t < NT; ++t){
    __syncthreads();
    stage_rows_bf16(Kl, Kb + (size_t)t * 64 * DKC, tid);
    __syncthreads();
    unsigned long long wb = 0;
    if constexpr (BITS) wb = bitsg[(size_t)qrow * NT + t];
    #pragma unroll
    for (int kt = 0; kt < 4; ++kt){
      const short8v kf0 = *(const short8v*)&Kl[swz(kt * 16 + ll, lh * 8)];
      const short8v kf1 = *(const short8v*)&Kl[swz(kt * 16 + ll, 32 + lh * 8)];
      f32x4 a = (f32x4){0.f, 0.f, 0.f, 0.f};
      a = __builtin_amdgcn_mfma_f32_16x16x32_bf16(kf0, qf[0], a, 0, 0, 0);
      a = __builtin_amdgcn_mfma_f32_16x16x32_bf16(kf1, qf[1], a, 0, 0, 0);
      #pragma unroll
      for (int j = 0; j < 4; ++j){
        const int bi = kt * 16 + lh * 4 + j;
        int keep;
        if constexpr (BITS) keep = (int)((wb >> bi) & 1ull);
        else                keep = maskg[(size_t)qrow * S_LEN + t * 64 + bi] != 0;
        sum += exp2f(keep ? a[j] * C_SC : NEGV);
      }
    }
  }
  sum += __shfl_xor(sum, 16, 64);
  sum += __shfl_xor(sum, 32, 64);
  const float rlog = __log2f(sum);

  f32x4 o[4];
  #pragma unroll
  for (int dt = 0; dt < 4; ++dt) o[dt] = (f32x4){0.f, 0.f, 0.f, 0.f};

  for (int t = 0; t < NT; ++t){
    __syncthreads();
    stage_rows_bf16(Kl, Kb + (size_t)t * 64 * DKC, tid);
    stage_vT_bf16 (Vt, Vb + (size_t)t * 64 * DKC, tid);
    __syncthreads();
    f32x4 acc[4];
    #pragma unroll
    for (int kt = 0; kt < 4; ++kt){
      const short8v kf0 = *(const short8v*)&Kl[swz(kt * 16 + ll, lh * 8)];
      const short8v kf1 = *(const short8v*)&Kl[swz(kt * 16 + ll, 32 + lh * 8)];
      f32x4 a = (f32x4){0.f, 0.f, 0.f, 0.f};
      a = __builtin_amdgcn_mfma_f32_16x16x32_bf16(kf0, qf[0], a, 0, 0, 0);
      a = __builtin_amdgcn_mfma_f32_16x16x32_bf16(kf1, qf[1], a, 0, 0, 0);
      acc[kt] = a;
    }
    unsigned long long wb = 0;
    if constexpr (BITS) wb = bitsg[(size_t)qrow * NT + t];
    #pragma unroll
    for (int kt = 0; kt < 4; ++kt){
      float p[4];
      #pragma unroll
      for (int j = 0; j < 4; ++j){
        const int bi = kt * 16 + lh * 4 + j;
        int keep;
        if constexpr (BITS) keep = (int)((wb >> bi) & 1ull);
        else                keep = maskg[(size_t)qrow * S_LEN + t * 64 + bi] != 0;
        p[j] = exp2f(keep ? fmaf(acc[kt][j], C_SC, -rlog) : NEGV);
      }
      f32x4 pv; pv[0]=p[0]; pv[1]=p[1]; pv[2]=p[2]; pv[3]=p[3];
      __builtin_nontemporal_store(pv, (f32x4*)&probsb[(size_t)qrow * S_LEN + t * 64 + kt * 16 + lh * 4]);
      short4 ps; ps.x=f2bf(p[0]); ps.y=f2bf(p[1]); ps.z=f2bf(p[2]); ps.w=f2bf(p[3]);
      *(short4*)&Pl[wid * 1024 + swz(ll, kt * 16 + lh * 4)] = ps;
    }
    asm volatile("s_waitcnt lgkmcnt(0)" ::: "memory");
    __builtin_amdgcn_sched_barrier(0);
    #pragma unroll
    for (int k32 = 0; k32 < 2; ++k32){
      const short8v pf = *(const short8v*)&Pl[wid * 1024 + swz(ll, k32 * 32 + lh * 8)];
      #pragma unroll
      for (int dt = 0; dt < 4; ++dt){
        const short8v vf = *(const short8v*)&Vt[swz(dt * 16 + ll, k32 * 32 + lh * 8)];
        o[dt] = __builtin_amdgcn_mfma_f32_16x16x32_bf16(pf, vf, o[dt], 0, 0, 0);
      }
    }
  }

  #pragma unroll
  for (int dt = 0; dt < 4; ++dt)
    #pragma unroll
    for (int j = 0; j < 4; ++j)
      __builtin_nontemporal_store(o[dt][j], &outb[(size_t)(qbase + wid * 16 + lh * 4 + j) * DKC + dt * 16 + ll]);
}

extern "C" void kernel_launch(void* const* d_in, const int* in_sizes, int n_in,
                              void* d_out, int out_size, void* d_ws, size_t ws_size,
                              hipStream_t stream) {
  const float* Q    = (const float*)d_in[0];
  const float* K    = (const float*)d_in[1];
  const float* V    = (const float*)d_in[2];
  const int*   mask = (const int*)d_in[3];

  float* out   = (float*)d_out;
  float* probs = out + (size_t)4 * 16 * 2048 * 64;

  const size_t bitsB = (size_t)S_LEN * S_LEN / 8;          // 512 KiB
  const size_t imgB  = (size_t)64 * NT * 4096 * 2;         // 16 MiB each
  unsigned long long* bits = (unsigned long long*)d_ws;
  short* Kimg = (short*)((char*)d_ws + bitsB);
  short* Vimg = (short*)((char*)d_ws + bitsB + imgB);
  short* Qimg = (short*)((char*)d_ws + bitsB + 2 * imgB);

  int mode;
  if      (ws_size >= bitsB + 3 * imgB) mode = 2;
  else if (ws_size >= bitsB)            mode = 1;
  else                                  mode = 0;

  if (mode == 2){
    kvq_convert<<<64 * NT, 256, 0, stream>>>(K, V, Q, mask, bits, Kimg, Vimg, Qimg);
    attn_f<<<64 * 32, 256, 0, stream>>>(Qimg, bits, Kimg, Vimg, out, probs);
  } else if (mode == 1){
    maskpack_kernel<<<256, 256, 0, stream>>>(mask, bits);
    attn_fb<1><<<64 * 32, 256, 0, stream>>>(Q, K, V, mask, bits, out, probs);
  } else {
    attn_fb<0><<<64 * 32, 256, 0, stream>>>(Q, K, V, mask, bits, out, probs);
  }
}